// Round 3
// baseline (3087.113 us; speedup 1.0000x reference)
//
#include <hip/hip_runtime.h>
#include <cstdint>
#include <cstddef>

// Problem dims (fixed). Inputs fp32, output fp32.
#define B_DIM 1024
#define T_DIM 32
#define V_DIM 1024
#define E_DIM 512
#define H_DIM 1024
#define O_DIM 1024

typedef unsigned short u16;
typedef unsigned long long u64;
typedef __attribute__((ext_vector_type(8))) __bf16 bf16x8;  // MFMA A/B frag
typedef __attribute__((ext_vector_type(4))) float f32x4;    // MFMA C/D frag

__device__ __forceinline__ float bf2f(u16 u) {
  union { unsigned int i; float f; } v; v.i = ((unsigned int)u) << 16; return v.f;
}
__device__ __forceinline__ u16 f2bf(float f) {
  union { float f; unsigned int i; } v; v.f = f;
  return (u16)((v.i + 0x7fffu + ((v.i >> 16) & 1u)) >> 16);  // RNE
}
// async global->LDS, 16B/lane; HW writes lds_base + lane*16 (wave-uniform base)
__device__ __forceinline__ void async_cp16(const void* g, void* l) {
  __builtin_amdgcn_global_load_lds(
      (const __attribute__((address_space(1))) void*)g,
      (__attribute__((address_space(3))) void*)l, 16, 0, 0);
}
// fast tanh via hw exp+rcp: exact at +-inf, |err| ~1e-6 (<< bf16 ulp)
__device__ __forceinline__ float fast_tanh(float v) {
  return 1.f - 2.f / (__expf(2.f * v) + 1.f);
}

// ---------------------------------------------------------------------------
// Convert W_hh and W_out fp32 -> bf16 (1M elems each).
// ---------------------------------------------------------------------------
__global__ __launch_bounds__(256) void convert_w2(
    const float* __restrict__ a, const float* __restrict__ b,
    u16* __restrict__ da, u16* __restrict__ db) {
  const int nq = 1048576 / 4;
  int i = blockIdx.x * blockDim.x + threadIdx.x;
  const int stride = gridDim.x * blockDim.x;
  const float4* a4 = (const float4*)a;
  const float4* b4 = (const float4*)b;
  for (; i < nq; i += stride) {
    float4 va = a4[i], vb = b4[i];
    ushort4 oa = {f2bf(va.x), f2bf(va.y), f2bf(va.z), f2bf(va.w)};
    ushort4 ob = {f2bf(vb.x), f2bf(vb.y), f2bf(vb.z), f2bf(vb.w)};
    *(ushort4*)(da + 4 * (size_t)i) = oa;
    *(ushort4*)(db + 4 * (size_t)i) = ob;
  }
}

// ---------------------------------------------------------------------------
// W_comb[h][v] = sum_e W_ih[h][e] * W_emb[e][v]  (VALU, verified)
// ---------------------------------------------------------------------------
__global__ __launch_bounds__(256) void wcomb_valu(
    const float* __restrict__ Wih, const float* __restrict__ Wemb,
    u16* __restrict__ Wc) {
  __shared__ __align__(16) float As[16][68];
  __shared__ __align__(16) float Bs[16][68];
  const int tx = threadIdx.x & 15, ty = threadIdx.x >> 4;
  const int v0 = blockIdx.x * 64, h0 = blockIdx.y * 64;
  float acc[4][4] = {};
  for (int kt = 0; kt < 32; ++kt) {  // K = 512
#pragma unroll
    for (int i = 0; i < 4; ++i) {
      int idx = threadIdx.x + i * 256;
      int row = idx >> 4, k = idx & 15;
      As[k][row] = Wih[(size_t)(h0 + row) * E_DIM + kt * 16 + k];
      Bs[k][row] = Wemb[(size_t)(kt * 16 + k) * V_DIM + v0 + row];
    }
    __syncthreads();
    for (int k = 0; k < 16; ++k) {
      float4 a = *(const float4*)&As[k][ty * 4];
      float4 b = *(const float4*)&Bs[k][tx * 4];
      const float av[4] = {a.x, a.y, a.z, a.w}, bv[4] = {b.x, b.y, b.z, b.w};
#pragma unroll
      for (int i = 0; i < 4; ++i)
#pragma unroll
        for (int j = 0; j < 4; ++j) acc[i][j] += av[i] * bv[j];
    }
    __syncthreads();
  }
#pragma unroll
  for (int i = 0; i < 4; ++i)
#pragma unroll
    for (int j = 0; j < 4; ++j)
      Wc[(size_t)(h0 + ty * 4 + i) * V_DIM + v0 + tx * 4 + j] = f2bf(acc[i][j]);
}

// b_comb[h] = W_ih[h,:].b_emb + b_ih[h]; block 0 also zeroes the barrier flags
__global__ __launch_bounds__(256) void bcomb_valu(
    const float* __restrict__ Wih, const float* __restrict__ bemb,
    const float* __restrict__ bih, float* __restrict__ bc,
    unsigned* __restrict__ flags) {
  if (blockIdx.x == 0) {  // 16 groups x 32-u32 stride = 512 u32
    flags[threadIdx.x] = 0;
    flags[threadIdx.x + 256] = 0;
  }
  int h = blockIdx.x * 256 + threadIdx.x;  // grid 4
  float s = 0.f;
  for (int e = 0; e < E_DIM; ++e) s += Wih[(size_t)h * E_DIM + e] * bemb[e];
  bc[h] = s + bih[h];
}

// ---------------------------------------------------------------------------
// x_proj [T,B,H] bf16: xp[t][b][h] = msg[b*32+t][:] . Wc[h][:] + bc[h]
// 128x128 MFMA tile, T2 XOR-swizzle on As/Bs (unchanged, passed in R1)
// ---------------------------------------------------------------------------
__global__ __launch_bounds__(256) void xproj_mfma(
    const float* __restrict__ msg, const u16* __restrict__ Wc,
    const float* __restrict__ bc, u16* __restrict__ xp) {
  __shared__ u16 As[128 * 64];
  __shared__ u16 Bs[128 * 64];
  const int tid = threadIdx.x, lane = tid & 63, w = tid >> 6;
  const int lrow = lane >> 4, lcol = lane & 15;
  const int n0 = blockIdx.x * 128, m0 = blockIdx.y * 128;
  const int mq = (w & 1) * 64, nq = (w >> 1) * 64;
  f32x4 acc[4][4] = {};
  const int r8 = lane >> 3, l7 = lane & 7;
  const int ar = tid >> 1, ak = (tid & 1) * 32;

  auto stageB = [&](int kk) {
#pragma unroll
    for (int i = 0; i < 4; ++i) {
      int ch = w * 4 + i;
      async_cp16(Wc + (size_t)(n0 + ch * 8 + r8) * V_DIM + kk * 64 + ((l7 ^ r8) << 3),
                 Bs + ch * 512);
    }
  };
  float4 areg[8];
  auto loadA = [&](int kk) {
    const float4* src = (const float4*)(msg + (size_t)(m0 + ar) * V_DIM + kk * 64 + ak);
#pragma unroll
    for (int i = 0; i < 8; ++i) areg[i] = src[i];
  };
  auto writeA = [&]() {
    u16 tmp[32];
#pragma unroll
    for (int i = 0; i < 8; ++i) {
      tmp[i * 4 + 0] = f2bf(areg[i].x);
      tmp[i * 4 + 1] = f2bf(areg[i].y);
      tmp[i * 4 + 2] = f2bf(areg[i].z);
      tmp[i * 4 + 3] = f2bf(areg[i].w);
    }
#pragma unroll
    for (int i = 0; i < 4; ++i) {
      int c = (ak + i * 8) ^ ((ar & 7) << 3);  // swizzled write
      *(uint4*)(As + (size_t)ar * 64 + c) = *(const uint4*)(tmp + i * 8);
    }
  };

  loadA(0);
  stageB(0);
  writeA();
  for (int kk = 0; kk < 16; ++kk) {
    __syncthreads();
    if (kk < 15) loadA(kk + 1);
#pragma unroll
    for (int ks = 0; ks < 2; ++ks) {
      const int kb = ks * 32 + lrow * 8;
      bf16x8 a[4], b[4];
#pragma unroll
      for (int mt = 0; mt < 4; ++mt) {
        int row = mq + mt * 16 + lcol;
        a[mt] = *(const bf16x8*)(As + row * 64 + (kb ^ ((row & 7) << 3)));
      }
#pragma unroll
      for (int nt = 0; nt < 4; ++nt) {
        int row = nq + nt * 16 + lcol;
        b[nt] = *(const bf16x8*)(Bs + row * 64 + (kb ^ ((row & 7) << 3)));
      }
#pragma unroll
      for (int mt = 0; mt < 4; ++mt)
#pragma unroll
        for (int nt = 0; nt < 4; ++nt)
          acc[mt][nt] = __builtin_amdgcn_mfma_f32_16x16x32_bf16(a[mt], b[nt], acc[mt][nt], 0, 0, 0);
    }
    __syncthreads();
    if (kk < 15) { stageB(kk + 1); writeA(); }
  }
  float bcv[4];
#pragma unroll
  for (int nt = 0; nt < 4; ++nt) bcv[nt] = bc[n0 + nq + nt * 16 + lcol];
#pragma unroll
  for (int mt = 0; mt < 4; ++mt)
#pragma unroll
    for (int rr = 0; rr < 4; ++rr) {
      int rg = m0 + mq + mt * 16 + lrow * 4 + rr;  // flat (b*T + t)
      int bI = rg >> 5, tI = rg & 31;
      u16* dst = xp + ((size_t)tI * B_DIM + bI) * H_DIM + n0 + nq;
#pragma unroll
      for (int nt = 0; nt < 4; ++nt)
        dst[nt * 16 + lcol] = f2bf(acc[mt][nt][rr] + bcv[nt]);
    }
}

// ---------------------------------------------------------------------------
// Persistent RNN, NO grid.sync. 256 blocks / 256 thr, 1 per CU.
// Batch rows partition into 16 independent groups of 16 blocks; only a
// 16-block flag barrier per step. h[t] overlays xp[t] (each block overwrites
// exactly the 8KB of xp[t] only it has read). h stores are agent-scope atomic
// (write-through to the L3 coherence point); readers use plain cached loads —
// safe because every address has a single-writer / first-read-after-write
// history (no stale line can exist in any reader cache; xproj's dirty lines
// were flushed at its kernel boundary).
// W slice (64x1024, 128 KB) LDS-resident all steps; A chunks triple-buffered
// with counted vmcnt(4) + raw s_barrier. LDS = 131072 + 3*8192 = 155648 B.
// ---------------------------------------------------------------------------
__global__ __launch_bounds__(256, 1) void rnn_fused(
    const u16* __restrict__ Whh_b, const u16* __restrict__ Wout_b,
    u16* __restrict__ xp, const float* __restrict__ bhh,
    const float* __restrict__ bout, unsigned* __restrict__ flags,
    float* __restrict__ outp) {
  __shared__ __align__(16) u16 Wlds[64 * 1024];   // 128 KB, resident W rows n0..n0+63
  __shared__ __align__(16) u16 Abuf[3][64 * 64];  // 3 x 8 KB rolling A chunks
  const int tid = threadIdx.x, lane = tid & 63, w = tid >> 6;
  const int lrow = lane >> 4, lcol = lane & 15;
  const int l7 = lane & 7, r8 = lane >> 3;
  const int bid = blockIdx.x;
  // group->same-XCD swizzle (perf heuristic only; correctness mapping-free)
  const int g = ((bid & 7) << 1) | ((bid >> 3) & 1);  // m-group 0..15
  const int nb = bid >> 4;                            // n-tile 0..15
  const int m0 = g * 64, n0 = nb * 64;
  const int mq = (w & 1) * 32, nq = (w >> 1) * 32;

  // Stage 64x1024 W slice (swizzled via source col, LDS linear). 32 rounds.
  auto stageW = [&](const u16* Wsrc) {
#pragma unroll 4
    for (int pp = 0; pp < 32; ++pp) {
      int r = pp * 2 + (w >> 1);
      int cb = ((w & 1) * 1024 + lane * 16) ^ ((r & 7) << 4);  // bytes
      async_cp16(Wsrc + (size_t)(n0 + r) * H_DIM + (cb >> 1),
                 Wlds + pp * 2048 + w * 512);
    }
  };
  // Stage one 64x64 A chunk (rows m0.., cols kk*64..), source pre-swizzled.
  auto stageA = [&](const u16* hin, int kk, int bufi) {
#pragma unroll
    for (int p = 0; p < 2; ++p) {
      int r = p * 32 + w * 8 + r8;
      async_cp16(hin + (size_t)(m0 + r) * H_DIM + kk * 64 + ((l7 ^ r8) << 3),
                 Abuf[bufi] + p * 2048 + w * 512);
    }
  };

  const int rA0 = mq + lcol, rA1 = mq + 16 + lcol;
  const int rB0 = nq + lcol, rB1 = nq + 16 + lcol;
  const int sA0 = (rA0 & 7) << 3, sA1 = (rA1 & 7) << 3;
  const int sB0 = (rB0 & 7) << 3, sB1 = (rB1 & 7) << 3;

  f32x4 acc[2][2];
  auto kchunk = [&](const u16* Ab, int kk) {
#pragma unroll
    for (int ks = 0; ks < 2; ++ks) {
      const int ca = ks * 32 + lrow * 8;
      const int cw = kk * 64 + ks * 32 + lrow * 8;
      bf16x8 a0 = *(const bf16x8*)(Ab + rA0 * 64 + (ca ^ sA0));
      bf16x8 a1 = *(const bf16x8*)(Ab + rA1 * 64 + (ca ^ sA1));
      bf16x8 b0 = *(const bf16x8*)(Wlds + rB0 * 1024 + (cw ^ sB0));
      bf16x8 b1 = *(const bf16x8*)(Wlds + rB1 * 1024 + (cw ^ sB1));
      acc[0][0] = __builtin_amdgcn_mfma_f32_16x16x32_bf16(a0, b0, acc[0][0], 0, 0, 0);
      acc[0][1] = __builtin_amdgcn_mfma_f32_16x16x32_bf16(a0, b1, acc[0][1], 0, 0, 0);
      acc[1][0] = __builtin_amdgcn_mfma_f32_16x16x32_bf16(a1, b0, acc[1][0], 0, 0, 0);
      acc[1][1] = __builtin_amdgcn_mfma_f32_16x16x32_bf16(a1, b1, acc[1][1], 0, 0, 0);
    }
  };
  // Depth-3 rolling pipeline, counted vmcnt (2 loads/wave/chunk). Counted
  // waits only ever over-drain (older loads ahead in queue), never under.
  auto kloop = [&](const u16* hin) {
    stageA(hin, 0, 0); stageA(hin, 1, 1); stageA(hin, 2, 2);
#pragma unroll
    for (int kk = 0; kk < 16; ++kk) {
      if (kk <= 13)      asm volatile("s_waitcnt vmcnt(4)" ::: "memory");
      else if (kk == 14) asm volatile("s_waitcnt vmcnt(2)" ::: "memory");
      else               asm volatile("s_waitcnt vmcnt(0)" ::: "memory");
      __builtin_amdgcn_s_barrier();   // chunk kk LDS-visible to all waves
      kchunk(Abuf[kk % 3], kk);
      __builtin_amdgcn_s_barrier();   // all reads of buf kk%3 done
      if (kk <= 12) stageA(hin, kk + 3, kk % 3);
    }
  };

  stageW(Whh_b);  // drained by t=0 epilogue's syncthreads, LDS-visible by t=1
  const float bv0 = bhh[n0 + nq + lcol], bv1 = bhh[n0 + nq + 16 + lcol];

  for (int t = 0; t < T_DIM; ++t) {
    u16* slot = xp + (size_t)t * (B_DIM * H_DIM);  // xp[t], becomes h[t]
    // x_t epilogue values (own tile of xp[t], read before overlay-write)
    u16 xv[2][2][4];
#pragma unroll
    for (int mt = 0; mt < 2; ++mt)
#pragma unroll
      for (int rr = 0; rr < 4; ++rr) {
        int row = m0 + mq + mt * 16 + lrow * 4 + rr;
#pragma unroll
        for (int nt = 0; nt < 2; ++nt)
          xv[mt][nt][rr] = slot[(size_t)row * H_DIM + n0 + nq + nt * 16 + lcol];
      }
#pragma unroll
    for (int i = 0; i < 2; ++i)
#pragma unroll
      for (int j = 0; j < 2; ++j) acc[i][j] = (f32x4){0.f, 0.f, 0.f, 0.f};
    if (t > 0) kloop(xp + (size_t)(t - 1) * (B_DIM * H_DIM));  // h[t-1]

    // epilogue: h = tanh(acc + b_hh + x_t) -> assemble tile in LDS
    u16* At = (u16*)Abuf;  // reuse 8 KB, all A reads done
#pragma unroll
    for (int mt = 0; mt < 2; ++mt)
#pragma unroll
      for (int rr = 0; rr < 4; ++rr) {
        int row = mq + mt * 16 + lrow * 4 + rr;  // tile-local
#pragma unroll
        for (int nt = 0; nt < 2; ++nt) {
          int col = nq + nt * 16 + lcol;
          float v = acc[mt][nt][rr] + (nt ? bv1 : bv0) + bf2f(xv[mt][nt][rr]);
          At[row * 64 + col] = f2bf(fast_tanh(v));
        }
      }
    __syncthreads();
    {  // agent-visible stores: 32 B/thread as 4x 8B atomic (write-through)
      int row = tid >> 2, ce = (tid & 3) * 16;  // 16 elems = 32 B per thread
      const u64* src = (const u64*)(At + row * 64 + ce);
      u64* gp = (u64*)(slot + (size_t)(m0 + row) * H_DIM + n0 + ce);
#pragma unroll
      for (int q = 0; q < 4; ++q)
        __hip_atomic_store(&gp[q], src[q], __ATOMIC_RELAXED,
                           __HIP_MEMORY_SCOPE_AGENT);
      asm volatile("s_waitcnt vmcnt(0)" ::: "memory");  // data at coherence pt
    }
    __syncthreads();  // all waves' stores drained
    if (w == 0) {     // group flag barrier (16 blocks)
      if (lane == 0)
        __hip_atomic_store(&flags[g * 32 + nb], (unsigned)(t + 1),
                           __ATOMIC_RELAXED, __HIP_MEMORY_SCOPE_AGENT);
      const unsigned tgt = (unsigned)(t + 1);
      int ok;
      do {
        unsigned v = 0xFFFFFFFFu;
        if (lane < 16)
          v = __hip_atomic_load(&flags[g * 32 + lane], __ATOMIC_RELAXED,
                                __HIP_MEMORY_SCOPE_AGENT);
        ok = __all(v >= tgt);
      } while (!ok);
      asm volatile("" ::: "memory");  // no load hoisting above the poll
    }
    __syncthreads();  // release block; next step's loads ordered after
  }

  // ---- output GEMM: out = h31 . W_out^T + b_out (fp32) ----
  const float bo0 = bout[n0 + nq + lcol], bo1 = bout[n0 + nq + 16 + lcol];
#pragma unroll
  for (int i = 0; i < 2; ++i)
#pragma unroll
    for (int j = 0; j < 2; ++j) acc[i][j] = (f32x4){0.f, 0.f, 0.f, 0.f};
  stageW(Wout_b);  // 32 loads, oldest in queue -> drained by kk=0's vmcnt(4)
  kloop(xp + (size_t)31 * (B_DIM * H_DIM));  // h[31]
#pragma unroll
  for (int mt = 0; mt < 2; ++mt)
#pragma unroll
    for (int rr = 0; rr < 4; ++rr) {
      int row = m0 + mq + mt * 16 + lrow * 4 + rr;
#pragma unroll
      for (int nt = 0; nt < 2; ++nt) {
        int col = n0 + nq + nt * 16 + lcol;
        outp[(size_t)row * O_DIM + col] = acc[mt][nt][rr] + (nt ? bo1 : bo0);
      }
    }
}

// ---------------------------------------------------------------------------
extern "C" void kernel_launch(void* const* d_in, const int* in_sizes, int n_in,
                              void* d_out, int out_size, void* d_ws, size_t ws_size,
                              hipStream_t stream) {
  const float* msg  = (const float*)d_in[0];
  const float* Wemb = (const float*)d_in[1];
  const float* bemb = (const float*)d_in[2];
  const float* Wih  = (const float*)d_in[3];
  const float* bih  = (const float*)d_in[4];
  const float* Whh  = (const float*)d_in[5];
  const float* bhh  = (const float*)d_in[6];
  const float* Wout = (const float*)d_in[7];
  const float* bout = (const float*)d_in[8];
  char* ws = (char*)d_ws;

  // ws layout (bytes)
  float* bc       = (float*)ws;               // 4 KB
  u16* Wc         = (u16*)(ws + 4096);        // 2 MB
  u16* Whh_b      = (u16*)(ws + 2101248);     // 2 MB
  u16* Wout_b     = (u16*)(ws + 4198400);     // 2 MB
  unsigned* flags = (unsigned*)(ws + 6295552);// 2 KB (16 groups x 32 u32)
  u16* xp         = (u16*)(ws + 10489856);    // 64 MB (xp[t] becomes h[t])
  const size_t NEED = 10489856 + 67108864;
  if (ws_size < NEED) return;

  convert_w2<<<512, 256, 0, stream>>>(Whh, Wout, Whh_b, Wout_b);
  wcomb_valu<<<dim3(16, 16), 256, 0, stream>>>(Wih, Wemb, Wc);
  bcomb_valu<<<4, 256, 0, stream>>>(Wih, bemb, bih, bc, flags);
  xproj_mfma<<<dim3(8, 256), 256, 0, stream>>>(msg, Wc, bc, xp);

  // persistent kernel: 32 RNN steps + output GEMM (coop launch only for the
  // co-residency guarantee; no grid.sync inside)
  const u16* a_whh = Whh_b; const u16* a_wout = Wout_b; u16* a_xp = xp;
  const float* a_bhh = bhh; const float* a_bout = bout;
  unsigned* a_fl = flags; float* a_out = (float*)d_out;
  void* kargs[] = {(void*)&a_whh, (void*)&a_wout, (void*)&a_xp,
                   (void*)&a_bhh, (void*)&a_bout, (void*)&a_fl, (void*)&a_out};
  (void)hipLaunchCooperativeKernel((const void*)rnn_fused, dim3(256), dim3(256),
                                   kargs, 0, stream);
}

// Round 4
// 2965.740 us; speedup vs baseline: 1.0409x; 1.0409x over previous
//
#include <hip/hip_runtime.h>
#include <cstdint>
#include <cstddef>

// Problem dims (fixed). Inputs fp32, output fp32.
#define B_DIM 1024
#define T_DIM 32
#define V_DIM 1024
#define E_DIM 512
#define H_DIM 1024
#define O_DIM 1024

typedef unsigned short u16;
typedef unsigned long long u64;
typedef __attribute__((ext_vector_type(8))) __bf16 bf16x8;  // MFMA A/B frag
typedef __attribute__((ext_vector_type(4))) float f32x4;    // MFMA C/D frag

__device__ __forceinline__ float bf2f(u16 u) {
  union { unsigned int i; float f; } v; v.i = ((unsigned int)u) << 16; return v.f;
}
__device__ __forceinline__ u16 f2bf(float f) {
  union { float f; unsigned int i; } v; v.f = f;
  return (u16)((v.i + 0x7fffu + ((v.i >> 16) & 1u)) >> 16);  // RNE
}
// async global->LDS, 16B/lane; HW writes lds_base + lane*16 (wave-uniform base)
__device__ __forceinline__ void async_cp16(const void* g, void* l) {
  __builtin_amdgcn_global_load_lds(
      (const __attribute__((address_space(1))) void*)g,
      (__attribute__((address_space(3))) void*)l, 16, 0, 0);
}
// fast tanh via hw exp+rcp: exact at +-inf, |err| ~1e-6 (<< bf16 ulp)
__device__ __forceinline__ float fast_tanh(float v) {
  return 1.f - 2.f / (__expf(2.f * v) + 1.f);
}

// ---------------------------------------------------------------------------
// Convert W_hh and W_out fp32 -> bf16 (1M elems each).
// ---------------------------------------------------------------------------
__global__ __launch_bounds__(256) void convert_w2(
    const float* __restrict__ a, const float* __restrict__ b,
    u16* __restrict__ da, u16* __restrict__ db) {
  const int nq = 1048576 / 4;
  int i = blockIdx.x * blockDim.x + threadIdx.x;
  const int stride = gridDim.x * blockDim.x;
  const float4* a4 = (const float4*)a;
  const float4* b4 = (const float4*)b;
  for (; i < nq; i += stride) {
    float4 va = a4[i], vb = b4[i];
    ushort4 oa = {f2bf(va.x), f2bf(va.y), f2bf(va.z), f2bf(va.w)};
    ushort4 ob = {f2bf(vb.x), f2bf(vb.y), f2bf(vb.z), f2bf(vb.w)};
    *(ushort4*)(da + 4 * (size_t)i) = oa;
    *(ushort4*)(db + 4 * (size_t)i) = ob;
  }
}

// ---------------------------------------------------------------------------
// W_comb[h][v] = sum_e W_ih[h][e] * W_emb[e][v]  (VALU, verified)
// ---------------------------------------------------------------------------
__global__ __launch_bounds__(256) void wcomb_valu(
    const float* __restrict__ Wih, const float* __restrict__ Wemb,
    u16* __restrict__ Wc) {
  __shared__ __align__(16) float As[16][68];
  __shared__ __align__(16) float Bs[16][68];
  const int tx = threadIdx.x & 15, ty = threadIdx.x >> 4;
  const int v0 = blockIdx.x * 64, h0 = blockIdx.y * 64;
  float acc[4][4] = {};
  for (int kt = 0; kt < 32; ++kt) {  // K = 512
#pragma unroll
    for (int i = 0; i < 4; ++i) {
      int idx = threadIdx.x + i * 256;
      int row = idx >> 4, k = idx & 15;
      As[k][row] = Wih[(size_t)(h0 + row) * E_DIM + kt * 16 + k];
      Bs[k][row] = Wemb[(size_t)(kt * 16 + k) * V_DIM + v0 + row];
    }
    __syncthreads();
    for (int k = 0; k < 16; ++k) {
      float4 a = *(const float4*)&As[k][ty * 4];
      float4 b = *(const float4*)&Bs[k][tx * 4];
      const float av[4] = {a.x, a.y, a.z, a.w}, bv[4] = {b.x, b.y, b.z, b.w};
#pragma unroll
      for (int i = 0; i < 4; ++i)
#pragma unroll
        for (int j = 0; j < 4; ++j) acc[i][j] += av[i] * bv[j];
    }
    __syncthreads();
  }
#pragma unroll
  for (int i = 0; i < 4; ++i)
#pragma unroll
    for (int j = 0; j < 4; ++j)
      Wc[(size_t)(h0 + ty * 4 + i) * V_DIM + v0 + tx * 4 + j] = f2bf(acc[i][j]);
}

// b_comb[h] = W_ih[h,:].b_emb + b_ih[h]; block 0 also zeroes discovery+flags
__global__ __launch_bounds__(256) void bcomb_valu(
    const float* __restrict__ Wih, const float* __restrict__ bemb,
    const float* __restrict__ bih, float* __restrict__ bc,
    unsigned* __restrict__ flags) {
  if (blockIdx.x == 0) {  // [0..255]=xcc table, [256]=counter, [512..]=step flags
    flags[threadIdx.x] = 0;
    flags[threadIdx.x + 256] = 0;
    flags[threadIdx.x + 512] = 0;
    flags[threadIdx.x + 768] = 0;
  }
  int h = blockIdx.x * 256 + threadIdx.x;  // grid 4
  float s = 0.f;
  for (int e = 0; e < E_DIM; ++e) s += Wih[(size_t)h * E_DIM + e] * bemb[e];
  bc[h] = s + bih[h];
}

// ---------------------------------------------------------------------------
// x_proj [T,B,H] bf16: xp[t][b][h] = msg[b*32+t][:] . Wc[h][:] + bc[h]
// 128x128 MFMA tile, T2 XOR-swizzle on As/Bs (unchanged, verified)
// ---------------------------------------------------------------------------
__global__ __launch_bounds__(256) void xproj_mfma(
    const float* __restrict__ msg, const u16* __restrict__ Wc,
    const float* __restrict__ bc, u16* __restrict__ xp) {
  __shared__ u16 As[128 * 64];
  __shared__ u16 Bs[128 * 64];
  const int tid = threadIdx.x, lane = tid & 63, w = tid >> 6;
  const int lrow = lane >> 4, lcol = lane & 15;
  const int n0 = blockIdx.x * 128, m0 = blockIdx.y * 128;
  const int mq = (w & 1) * 64, nq = (w >> 1) * 64;
  f32x4 acc[4][4] = {};
  const int r8 = lane >> 3, l7 = lane & 7;
  const int ar = tid >> 1, ak = (tid & 1) * 32;

  auto stageB = [&](int kk) {
#pragma unroll
    for (int i = 0; i < 4; ++i) {
      int ch = w * 4 + i;
      async_cp16(Wc + (size_t)(n0 + ch * 8 + r8) * V_DIM + kk * 64 + ((l7 ^ r8) << 3),
                 Bs + ch * 512);
    }
  };
  float4 areg[8];
  auto loadA = [&](int kk) {
    const float4* src = (const float4*)(msg + (size_t)(m0 + ar) * V_DIM + kk * 64 + ak);
#pragma unroll
    for (int i = 0; i < 8; ++i) areg[i] = src[i];
  };
  auto writeA = [&]() {
    u16 tmp[32];
#pragma unroll
    for (int i = 0; i < 8; ++i) {
      tmp[i * 4 + 0] = f2bf(areg[i].x);
      tmp[i * 4 + 1] = f2bf(areg[i].y);
      tmp[i * 4 + 2] = f2bf(areg[i].z);
      tmp[i * 4 + 3] = f2bf(areg[i].w);
    }
#pragma unroll
    for (int i = 0; i < 4; ++i) {
      int c = (ak + i * 8) ^ ((ar & 7) << 3);  // swizzled write
      *(uint4*)(As + (size_t)ar * 64 + c) = *(const uint4*)(tmp + i * 8);
    }
  };

  loadA(0);
  stageB(0);
  writeA();
  for (int kk = 0; kk < 16; ++kk) {
    __syncthreads();
    if (kk < 15) loadA(kk + 1);
#pragma unroll
    for (int ks = 0; ks < 2; ++ks) {
      const int kb = ks * 32 + lrow * 8;
      bf16x8 a[4], b[4];
#pragma unroll
      for (int mt = 0; mt < 4; ++mt) {
        int row = mq + mt * 16 + lcol;
        a[mt] = *(const bf16x8*)(As + row * 64 + (kb ^ ((row & 7) << 3)));
      }
#pragma unroll
      for (int nt = 0; nt < 4; ++nt) {
        int row = nq + nt * 16 + lcol;
        b[nt] = *(const bf16x8*)(Bs + row * 64 + (kb ^ ((row & 7) << 3)));
      }
#pragma unroll
      for (int mt = 0; mt < 4; ++mt)
#pragma unroll
        for (int nt = 0; nt < 4; ++nt)
          acc[mt][nt] = __builtin_amdgcn_mfma_f32_16x16x32_bf16(a[mt], b[nt], acc[mt][nt], 0, 0, 0);
    }
    __syncthreads();
    if (kk < 15) { stageB(kk + 1); writeA(); }
  }
  float bcv[4];
#pragma unroll
  for (int nt = 0; nt < 4; ++nt) bcv[nt] = bc[n0 + nq + nt * 16 + lcol];
#pragma unroll
  for (int mt = 0; mt < 4; ++mt)
#pragma unroll
    for (int rr = 0; rr < 4; ++rr) {
      int rg = m0 + mq + mt * 16 + lrow * 4 + rr;  // flat (b*T + t)
      int bI = rg >> 5, tI = rg & 31;
      u16* dst = xp + ((size_t)tI * B_DIM + bI) * H_DIM + n0 + nq;
#pragma unroll
      for (int nt = 0; nt < 4; ++nt)
        dst[nt * 16 + lcol] = f2bf(acc[mt][nt][rr] + bcv[nt]);
    }
}

// ---------------------------------------------------------------------------
// Persistent RNN. 256 blocks / 256 thr, 1 per CU. 16 groups x 16 blocks
// exchange h once per step via a flag barrier. NEW (R4): one-time XCD
// discovery via HW_REG_XCC_ID -- blocks sort by (xcc, bid) and take group =
// rank/16, so each group's 16 members share one XCD whenever possible. A
// verified same-XCD group uses PLAIN write-back stores (fast, full-line, L2-
// coherent within the XCD; reader caches hold no stale copy: every exchanged
// address is own-write or first-touch-after-write). Non-uniform groups fall
// back to the R3 atomic write-through path (proven correct, just slower).
// W slice (64x1024, 128 KB) LDS-resident; A chunks triple-buffered with
// counted vmcnt(4) + raw s_barrier. LDS = 131072 + 3*8192 + 48 = 155696 B.
// ---------------------------------------------------------------------------
__global__ __launch_bounds__(256, 1) void rnn_fused(
    const u16* __restrict__ Whh_b, const u16* __restrict__ Wout_b,
    u16* __restrict__ xp, const float* __restrict__ bhh,
    const float* __restrict__ bout, unsigned* __restrict__ flags,
    float* __restrict__ outp) {
  __shared__ __align__(16) u16 Wlds[64 * 1024];   // 128 KB, resident W rows n0..n0+63
  __shared__ __align__(16) u16 Abuf[3][64 * 64];  // 3 x 8 KB rolling A chunks
  __shared__ int disc[12];
  const int tid = threadIdx.x, lane = tid & 63, w = tid >> 6;
  const int lrow = lane >> 4, lcol = lane & 15;
  const int l7 = lane & 7, r8 = lane >> 3;
  const int bid = blockIdx.x;

  // ---- one-time XCD discovery ----
  unsigned my_xcc;
  asm volatile("s_getreg_b32 %0, hwreg(HW_REG_XCC_ID)" : "=s"(my_xcc));
  if (tid == 0) {
    __hip_atomic_store(&flags[bid], my_xcc + 1u, __ATOMIC_RELAXED,
                       __HIP_MEMORY_SCOPE_AGENT);
    asm volatile("s_waitcnt vmcnt(0)" ::: "memory");  // table entry at L3
    __hip_atomic_fetch_add(&flags[256], 1u, __ATOMIC_RELAXED,
                           __HIP_MEMORY_SCOPE_AGENT);
    while (__hip_atomic_load(&flags[256], __ATOMIC_RELAXED,
                             __HIP_MEMORY_SCOPE_AGENT) < 256u)
      __builtin_amdgcn_s_sleep(2);
  }
  __syncthreads();
  {
    unsigned e = __hip_atomic_load(&flags[tid], __ATOMIC_RELAXED,
                                   __HIP_MEMORY_SCOPE_AGENT) - 1u;
    bool pl = e < my_xcc;                       // strictly lower xcc
    bool pr = pl || (e == my_xcc && tid < bid); // sort key (xcc, bid)
    bool pe = (e == my_xcc);
    u64 br = __ballot(pr), bl = __ballot(pl), be = __ballot(pe);
    if (lane == 0) {
      disc[w] = (int)__popcll(br);
      disc[4 + w] = (int)__popcll(bl);
      disc[8 + w] = (int)__popcll(be);
    }
  }
  __syncthreads();
  const int rank = disc[0] + disc[1] + disc[2] + disc[3];
  const int cLow = disc[4] + disc[5] + disc[6] + disc[7];
  const int cEq  = disc[8] + disc[9] + disc[10] + disc[11];
  const int gid = rank >> 4, nb = rank & 15;
  // group uniform iff its 16 ranks lie inside my xcc's rank interval
  const bool fastp = (gid * 16 >= cLow) && (gid * 16 + 16 <= cLow + cEq);
  const int m0 = gid * 64, n0 = nb * 64;
  const int mq = (w & 1) * 32, nq = (w >> 1) * 32;
  unsigned* sf = flags + 512;  // step flags, 16 groups x 32 stride

  // Stage 64x1024 W slice (swizzled via source col, LDS linear). 32 rounds.
  auto stageW = [&](const u16* Wsrc) {
#pragma unroll 4
    for (int pp = 0; pp < 32; ++pp) {
      int r = pp * 2 + (w >> 1);
      int cb = ((w & 1) * 1024 + lane * 16) ^ ((r & 7) << 4);  // bytes
      async_cp16(Wsrc + (size_t)(n0 + r) * H_DIM + (cb >> 1),
                 Wlds + pp * 2048 + w * 512);
    }
  };
  // Stage one 64x64 A chunk (rows m0.., cols kk*64..), source pre-swizzled.
  auto stageA = [&](const u16* hin, int kk, int bufi) {
#pragma unroll
    for (int p = 0; p < 2; ++p) {
      int r = p * 32 + w * 8 + r8;
      async_cp16(hin + (size_t)(m0 + r) * H_DIM + kk * 64 + ((l7 ^ r8) << 3),
                 Abuf[bufi] + p * 2048 + w * 512);
    }
  };

  const int rA0 = mq + lcol, rA1 = mq + 16 + lcol;
  const int rB0 = nq + lcol, rB1 = nq + 16 + lcol;
  const int sA0 = (rA0 & 7) << 3, sA1 = (rA1 & 7) << 3;
  const int sB0 = (rB0 & 7) << 3, sB1 = (rB1 & 7) << 3;

  f32x4 acc[2][2];
  auto kchunk = [&](const u16* Ab, int kk) {
#pragma unroll
    for (int ks = 0; ks < 2; ++ks) {
      const int ca = ks * 32 + lrow * 8;
      const int cw = kk * 64 + ks * 32 + lrow * 8;
      bf16x8 a0 = *(const bf16x8*)(Ab + rA0 * 64 + (ca ^ sA0));
      bf16x8 a1 = *(const bf16x8*)(Ab + rA1 * 64 + (ca ^ sA1));
      bf16x8 b0 = *(const bf16x8*)(Wlds + rB0 * 1024 + (cw ^ sB0));
      bf16x8 b1 = *(const bf16x8*)(Wlds + rB1 * 1024 + (cw ^ sB1));
      acc[0][0] = __builtin_amdgcn_mfma_f32_16x16x32_bf16(a0, b0, acc[0][0], 0, 0, 0);
      acc[0][1] = __builtin_amdgcn_mfma_f32_16x16x32_bf16(a0, b1, acc[0][1], 0, 0, 0);
      acc[1][0] = __builtin_amdgcn_mfma_f32_16x16x32_bf16(a1, b0, acc[1][0], 0, 0, 0);
      acc[1][1] = __builtin_amdgcn_mfma_f32_16x16x32_bf16(a1, b1, acc[1][1], 0, 0, 0);
    }
  };
  // Depth-3 rolling pipeline, counted vmcnt (2 loads/wave/chunk). Counted
  // waits only ever over-drain (older loads ahead in queue), never under.
  auto kloop = [&](const u16* hin) {
    stageA(hin, 0, 0); stageA(hin, 1, 1); stageA(hin, 2, 2);
#pragma unroll
    for (int kk = 0; kk < 16; ++kk) {
      if (kk <= 13)      asm volatile("s_waitcnt vmcnt(4)" ::: "memory");
      else if (kk == 14) asm volatile("s_waitcnt vmcnt(2)" ::: "memory");
      else               asm volatile("s_waitcnt vmcnt(0)" ::: "memory");
      __builtin_amdgcn_s_barrier();   // chunk kk LDS-visible to all waves
      kchunk(Abuf[kk % 3], kk);
      __builtin_amdgcn_s_barrier();   // all reads of buf kk%3 done
      if (kk <= 12) stageA(hin, kk + 3, kk % 3);
    }
  };

  stageW(Whh_b);  // drained before first kchunk by kloop's counted vmcnt
  const float bv0 = bhh[n0 + nq + lcol], bv1 = bhh[n0 + nq + 16 + lcol];

  for (int t = 0; t < T_DIM; ++t) {
    u16* slot = xp + (size_t)t * (B_DIM * H_DIM);  // xp[t], becomes h[t]
    // x_t epilogue values (own tile of xp[t], read before overlay-write)
    u16 xv[2][2][4];
#pragma unroll
    for (int mt = 0; mt < 2; ++mt)
#pragma unroll
      for (int rr = 0; rr < 4; ++rr) {
        int row = m0 + mq + mt * 16 + lrow * 4 + rr;
#pragma unroll
        for (int nt = 0; nt < 2; ++nt)
          xv[mt][nt][rr] = slot[(size_t)row * H_DIM + n0 + nq + nt * 16 + lcol];
      }
#pragma unroll
    for (int i = 0; i < 2; ++i)
#pragma unroll
      for (int j = 0; j < 2; ++j) acc[i][j] = (f32x4){0.f, 0.f, 0.f, 0.f};
    if (t > 0) kloop(xp + (size_t)(t - 1) * (B_DIM * H_DIM));  // h[t-1]

    // epilogue: h = tanh(acc + b_hh + x_t) -> assemble tile in LDS
    u16* At = (u16*)Abuf;  // reuse 8 KB, all A reads done
#pragma unroll
    for (int mt = 0; mt < 2; ++mt)
#pragma unroll
      for (int rr = 0; rr < 4; ++rr) {
        int row = mq + mt * 16 + lrow * 4 + rr;  // tile-local
#pragma unroll
        for (int nt = 0; nt < 2; ++nt) {
          int col = nq + nt * 16 + lcol;
          float v = acc[mt][nt][rr] + (nt ? bv1 : bv0) + bf2f(xv[mt][nt][rr]);
          At[row * 64 + col] = f2bf(fast_tanh(v));
        }
      }
    __syncthreads();
    {
      int row = tid >> 2, ce = (tid & 3) * 16;  // 16 elems = 32 B per thread
      if (fastp) {  // plain write-back stores; same-XCD L2 is coherence pt
        const uint4* src = (const uint4*)(At + row * 64 + ce);
        uint4* gp = (uint4*)(slot + (size_t)(m0 + row) * H_DIM + n0 + ce);
        gp[0] = src[0];
        gp[1] = src[1];
      } else {      // cross-XCD group: write-through atomics (R3 path)
        const u64* src = (const u64*)(At + row * 64 + ce);
        u64* gp = (u64*)(slot + (size_t)(m0 + row) * H_DIM + n0 + ce);
#pragma unroll
        for (int q = 0; q < 4; ++q)
          __hip_atomic_store(&gp[q], src[q], __ATOMIC_RELAXED,
                             __HIP_MEMORY_SCOPE_AGENT);
      }
      asm volatile("s_waitcnt vmcnt(0)" ::: "memory");  // stores complete
    }
    __syncthreads();  // all waves' stores drained
    if (w == 0) {     // group flag barrier (16 blocks)
      if (lane == 0)
        __hip_atomic_store(&sf[gid * 32 + nb], (unsigned)(t + 1),
                           __ATOMIC_RELAXED, __HIP_MEMORY_SCOPE_AGENT);
      const unsigned tgt = (unsigned)(t + 1);
      int ok;
      do {
        unsigned v = 0xFFFFFFFFu;
        if (lane < 16)
          v = __hip_atomic_load(&sf[gid * 32 + lane], __ATOMIC_RELAXED,
                                __HIP_MEMORY_SCOPE_AGENT);
        ok = __all(v >= tgt);
      } while (!ok);
      asm volatile("" ::: "memory");  // no load hoisting above the poll
    }
    __syncthreads();  // release block; next step's loads ordered after
  }

  // ---- output GEMM: out = h31 . W_out^T + b_out (fp32) ----
  const float bo0 = bout[n0 + nq + lcol], bo1 = bout[n0 + nq + 16 + lcol];
#pragma unroll
  for (int i = 0; i < 2; ++i)
#pragma unroll
    for (int j = 0; j < 2; ++j) acc[i][j] = (f32x4){0.f, 0.f, 0.f, 0.f};
  stageW(Wout_b);  // 32 loads, oldest in queue -> drained by kk=0's vmcnt(4)
  kloop(xp + (size_t)31 * (B_DIM * H_DIM));  // h[31]
#pragma unroll
  for (int mt = 0; mt < 2; ++mt)
#pragma unroll
    for (int rr = 0; rr < 4; ++rr) {
      int row = m0 + mq + mt * 16 + lrow * 4 + rr;
#pragma unroll
      for (int nt = 0; nt < 2; ++nt) {
        int col = n0 + nq + nt * 16 + lcol;
        outp[(size_t)row * O_DIM + col] = acc[mt][nt][rr] + (nt ? bo1 : bo0);
      }
    }
}

// ---------------------------------------------------------------------------
extern "C" void kernel_launch(void* const* d_in, const int* in_sizes, int n_in,
                              void* d_out, int out_size, void* d_ws, size_t ws_size,
                              hipStream_t stream) {
  const float* msg  = (const float*)d_in[0];
  const float* Wemb = (const float*)d_in[1];
  const float* bemb = (const float*)d_in[2];
  const float* Wih  = (const float*)d_in[3];
  const float* bih  = (const float*)d_in[4];
  const float* Whh  = (const float*)d_in[5];
  const float* bhh  = (const float*)d_in[6];
  const float* Wout = (const float*)d_in[7];
  const float* bout = (const float*)d_in[8];
  char* ws = (char*)d_ws;

  // ws layout (bytes)
  float* bc       = (float*)ws;               // 4 KB
  u16* Wc         = (u16*)(ws + 4096);        // 2 MB
  u16* Whh_b      = (u16*)(ws + 2101248);     // 2 MB
  u16* Wout_b     = (u16*)(ws + 4198400);     // 2 MB
  unsigned* flags = (unsigned*)(ws + 6295552);// 4 KB (table+counter+step flags)
  u16* xp         = (u16*)(ws + 10489856);    // 64 MB (xp[t] becomes h[t])
  const size_t NEED = 10489856 + 67108864;
  if (ws_size < NEED) return;

  convert_w2<<<512, 256, 0, stream>>>(Whh, Wout, Whh_b, Wout_b);
  wcomb_valu<<<dim3(16, 16), 256, 0, stream>>>(Wih, Wemb, Wc);
  bcomb_valu<<<4, 256, 0, stream>>>(Wih, bemb, bih, bc, flags);
  xproj_mfma<<<dim3(8, 256), 256, 0, stream>>>(msg, Wc, bc, xp);

  // persistent kernel: 32 RNN steps + output GEMM (coop launch only for the
  // co-residency guarantee; no grid.sync inside)
  const u16* a_whh = Whh_b; const u16* a_wout = Wout_b; u16* a_xp = xp;
  const float* a_bhh = bhh; const float* a_bout = bout;
  unsigned* a_fl = flags; float* a_out = (float*)d_out;
  void* kargs[] = {(void*)&a_whh, (void*)&a_wout, (void*)&a_xp,
                   (void*)&a_bhh, (void*)&a_bout, (void*)&a_fl, (void*)&a_out};
  (void)hipLaunchCooperativeKernel((const void*)rnn_fused, dim3(256), dim3(256),
                                   kargs, 0, stream);
}

// Round 5
// 882.143 us; speedup vs baseline: 3.4996x; 3.3620x over previous
//
#include <hip/hip_runtime.h>
#include <cstdint>
#include <cstddef>

// Problem dims (fixed). Inputs fp32, output fp32.
#define B_DIM 1024
#define T_DIM 32
#define V_DIM 1024
#define E_DIM 512
#define H_DIM 1024
#define O_DIM 1024

typedef unsigned short u16;
typedef __attribute__((ext_vector_type(8))) __bf16 bf16x8;  // MFMA A/B frag
typedef __attribute__((ext_vector_type(4))) float f32x4;    // MFMA C/D frag

__device__ __forceinline__ float bf2f(u16 u) {
  union { unsigned int i; float f; } v; v.i = ((unsigned int)u) << 16; return v.f;
}
__device__ __forceinline__ u16 f2bf(float f) {
  union { float f; unsigned int i; } v; v.f = f;
  return (u16)((v.i + 0x7fffu + ((v.i >> 16) & 1u)) >> 16);  // RNE
}
// async global->LDS, 16B/lane; HW writes lds_base + lane*16 (wave-uniform base)
__device__ __forceinline__ void async_cp16(const void* g, void* l) {
  __builtin_amdgcn_global_load_lds(
      (const __attribute__((address_space(1))) void*)g,
      (__attribute__((address_space(3))) void*)l, 16, 0, 0);
}
// fast tanh via hw exp+rcp: exact at +-inf, |err| ~1e-6 (<< bf16 ulp)
__device__ __forceinline__ float fast_tanh(float v) {
  return 1.f - 2.f / (__expf(2.f * v) + 1.f);
}

// ---------------------------------------------------------------------------
// Convert W_hh and W_out fp32 -> bf16 (1M elems each).
// ---------------------------------------------------------------------------
__global__ __launch_bounds__(256) void convert_w2(
    const float* __restrict__ a, const float* __restrict__ b,
    u16* __restrict__ da, u16* __restrict__ db) {
  const int nq = 1048576 / 4;
  int i = blockIdx.x * blockDim.x + threadIdx.x;
  const int stride = gridDim.x * blockDim.x;
  const float4* a4 = (const float4*)a;
  const float4* b4 = (const float4*)b;
  for (; i < nq; i += stride) {
    float4 va = a4[i], vb = b4[i];
    ushort4 oa = {f2bf(va.x), f2bf(va.y), f2bf(va.z), f2bf(va.w)};
    ushort4 ob = {f2bf(vb.x), f2bf(vb.y), f2bf(vb.z), f2bf(vb.w)};
    *(ushort4*)(da + 4 * (size_t)i) = oa;
    *(ushort4*)(db + 4 * (size_t)i) = ob;
  }
}

// ---------------------------------------------------------------------------
// W_comb[h][v] = sum_e W_ih[h][e] * W_emb[e][v]  (VALU, verified)
// ---------------------------------------------------------------------------
__global__ __launch_bounds__(256) void wcomb_valu(
    const float* __restrict__ Wih, const float* __restrict__ Wemb,
    u16* __restrict__ Wc) {
  __shared__ __align__(16) float As[16][68];
  __shared__ __align__(16) float Bs[16][68];
  const int tx = threadIdx.x & 15, ty = threadIdx.x >> 4;
  const int v0 = blockIdx.x * 64, h0 = blockIdx.y * 64;
  float acc[4][4] = {};
  for (int kt = 0; kt < 32; ++kt) {  // K = 512
#pragma unroll
    for (int i = 0; i < 4; ++i) {
      int idx = threadIdx.x + i * 256;
      int row = idx >> 4, k = idx & 15;
      As[k][row] = Wih[(size_t)(h0 + row) * E_DIM + kt * 16 + k];
      Bs[k][row] = Wemb[(size_t)(kt * 16 + k) * V_DIM + v0 + row];
    }
    __syncthreads();
    for (int k = 0; k < 16; ++k) {
      float4 a = *(const float4*)&As[k][ty * 4];
      float4 b = *(const float4*)&Bs[k][tx * 4];
      const float av[4] = {a.x, a.y, a.z, a.w}, bv[4] = {b.x, b.y, b.z, b.w};
#pragma unroll
      for (int i = 0; i < 4; ++i)
#pragma unroll
        for (int j = 0; j < 4; ++j) acc[i][j] += av[i] * bv[j];
    }
    __syncthreads();
  }
#pragma unroll
  for (int i = 0; i < 4; ++i)
#pragma unroll
    for (int j = 0; j < 4; ++j)
      Wc[(size_t)(h0 + ty * 4 + i) * V_DIM + v0 + tx * 4 + j] = f2bf(acc[i][j]);
}

// b_comb[h] = W_ih[h,:].b_emb + b_ih[h]  (all fp32)
__global__ __launch_bounds__(256) void bcomb_valu(
    const float* __restrict__ Wih, const float* __restrict__ bemb,
    const float* __restrict__ bih, float* __restrict__ bc) {
  int h = blockIdx.x * 256 + threadIdx.x;  // grid 4
  float s = 0.f;
  for (int e = 0; e < E_DIM; ++e) s += Wih[(size_t)h * E_DIM + e] * bemb[e];
  bc[h] = s + bih[h];
}

// ---------------------------------------------------------------------------
// x_proj [T,B,H] bf16: xp[t][b][h] = msg[b*32+t][:] . Wc[h][:] + bc[h]
// 128x128 MFMA tile, T2 XOR-swizzle (verified). NEW: XCD-locality block-id
// remap. Linear id p -> xcd k = p&7 (dispatch heuristic). Assign m-tile =
// k*32 + (p>>3)>>3, n-tile = (p>>3)&7: each XCD owns a 32-m-tile band of msg
// (read ONCE into its L2, 16 MB), and the 8 n-blocks of one m-tile are
// id-adjacent on the SAME XCD -> A-tile (512 KB) fetched once, 8 L2 hits.
// Was: every XCD streamed all 134 MB of msg (FETCH 528 MB).
// ---------------------------------------------------------------------------
__global__ __launch_bounds__(256) void xproj_mfma(
    const float* __restrict__ msg, const u16* __restrict__ Wc,
    const float* __restrict__ bc, u16* __restrict__ xp) {
  __shared__ u16 As[128 * 64];
  __shared__ u16 Bs[128 * 64];
  const int tid = threadIdx.x, lane = tid & 63, w = tid >> 6;
  const int lrow = lane >> 4, lcol = lane & 15;
  const int p = blockIdx.y * gridDim.x + blockIdx.x;  // linear id, x fastest
  const int xk = p & 7, q = p >> 3;
  const int m0 = (xk * 32 + (q >> 3)) * 128;  // m-tile 0..255
  const int n0 = (q & 7) * 128;               // n-tile 0..7
  const int mq = (w & 1) * 64, nq = (w >> 1) * 64;
  f32x4 acc[4][4] = {};
  const int r8 = lane >> 3, l7 = lane & 7;
  const int ar = tid >> 1, ak = (tid & 1) * 32;

  auto stageB = [&](int kk) {
#pragma unroll
    for (int i = 0; i < 4; ++i) {
      int ch = w * 4 + i;
      async_cp16(Wc + (size_t)(n0 + ch * 8 + r8) * V_DIM + kk * 64 + ((l7 ^ r8) << 3),
                 Bs + ch * 512);
    }
  };
  float4 areg[8];
  auto loadA = [&](int kk) {
    const float4* src = (const float4*)(msg + (size_t)(m0 + ar) * V_DIM + kk * 64 + ak);
#pragma unroll
    for (int i = 0; i < 8; ++i) areg[i] = src[i];
  };
  auto writeA = [&]() {
    u16 tmp[32];
#pragma unroll
    for (int i = 0; i < 8; ++i) {
      tmp[i * 4 + 0] = f2bf(areg[i].x);
      tmp[i * 4 + 1] = f2bf(areg[i].y);
      tmp[i * 4 + 2] = f2bf(areg[i].z);
      tmp[i * 4 + 3] = f2bf(areg[i].w);
    }
#pragma unroll
    for (int i = 0; i < 4; ++i) {
      int c = (ak + i * 8) ^ ((ar & 7) << 3);  // swizzled write
      *(uint4*)(As + (size_t)ar * 64 + c) = *(const uint4*)(tmp + i * 8);
    }
  };

  loadA(0);
  stageB(0);
  writeA();
  for (int kk = 0; kk < 16; ++kk) {
    __syncthreads();
    if (kk < 15) loadA(kk + 1);
#pragma unroll
    for (int ks = 0; ks < 2; ++ks) {
      const int kb = ks * 32 + lrow * 8;
      bf16x8 a[4], b[4];
#pragma unroll
      for (int mt = 0; mt < 4; ++mt) {
        int row = mq + mt * 16 + lcol;
        a[mt] = *(const bf16x8*)(As + row * 64 + (kb ^ ((row & 7) << 3)));
      }
#pragma unroll
      for (int nt = 0; nt < 4; ++nt) {
        int row = nq + nt * 16 + lcol;
        b[nt] = *(const bf16x8*)(Bs + row * 64 + (kb ^ ((row & 7) << 3)));
      }
#pragma unroll
      for (int mt = 0; mt < 4; ++mt)
#pragma unroll
        for (int nt = 0; nt < 4; ++nt)
          acc[mt][nt] = __builtin_amdgcn_mfma_f32_16x16x32_bf16(a[mt], b[nt], acc[mt][nt], 0, 0, 0);
    }
    __syncthreads();
    if (kk < 15) { stageB(kk + 1); writeA(); }
  }
  float bcv[4];
#pragma unroll
  for (int nt = 0; nt < 4; ++nt) bcv[nt] = bc[n0 + nq + nt * 16 + lcol];
#pragma unroll
  for (int mt = 0; mt < 4; ++mt)
#pragma unroll
    for (int rr = 0; rr < 4; ++rr) {
      int rg = m0 + mq + mt * 16 + lrow * 4 + rr;  // flat (b*T + t)
      int bI = rg >> 5, tI = rg & 31;
      u16* dst = xp + ((size_t)tI * B_DIM + bI) * H_DIM + n0 + nq;
#pragma unroll
      for (int nt = 0; nt < 4; ++nt)
        dst[nt * 16 + lcol] = f2bf(acc[mt][nt][rr] + bcv[nt]);
    }
}

// ---------------------------------------------------------------------------
// One RNN step (or output GEMM): out = f(A.Bm^T + bias (+ x)).
// 64x64 tile, grid 16x16, kernel boundary = inter-step sync (beats every
// persistent-sync variant measured in R1/R3/R4). NEW vs R0:
//  - depth-3 counted-vmcnt pipeline (vmcnt(8) steady state, 4 loads/chunk/
//    wave) + raw s_barrier: load latency spans barriers instead of a full
//    vmcnt(0) drain per K-chunk  [T3/T4, verified in R3/R4 kloop]
//  - XOR-swizzled staging (source col) + swizzled ds_read: kills the 16-way
//    bank conflict of 128B-stride row-major tiles  [T2, verified]
//  - bf16 h-output assembled in LDS, stored as coalesced uint4 (32B/thread)
// ---------------------------------------------------------------------------
__global__ __launch_bounds__(256) void step_mfma(
    const u16* __restrict__ A, const u16* __restrict__ Bm,
    const u16* __restrict__ xrow, const float* __restrict__ bias,
    void* __restrict__ outp, int out_f32, int do_tanh) {
  __shared__ __align__(16) u16 Ab[3][64 * 64];  // 3 x 8 KB
  __shared__ __align__(16) u16 Bb[3][64 * 64];  // 3 x 8 KB
  const int tid = threadIdx.x, lane = tid & 63, w = tid >> 6;
  const int lrow = lane >> 4, lcol = lane & 15;
  const int l7 = lane & 7, r8 = lane >> 3;
  const int n0 = blockIdx.x * 64, m0 = blockIdx.y * 64;
  const int mq = (w & 1) * 32, nq = (w >> 1) * 32;
  f32x4 acc[2][2] = {};

  const int rA0 = mq + lcol, rA1 = mq + 16 + lcol;
  const int rB0 = nq + lcol, rB1 = nq + 16 + lcol;
  const int sA0 = (rA0 & 7) << 3, sA1 = (rA1 & 7) << 3;
  const int sB0 = (rB0 & 7) << 3, sB1 = (rB1 & 7) << 3;

  if (A != nullptr) {
    auto stage = [&](int kk, int bufi) {
#pragma unroll
      for (int pp = 0; pp < 2; ++pp) {
        int r = pp * 32 + w * 8 + r8;
        int sc = (l7 ^ r8) << 3;  // pre-swizzled source col (elems)
        async_cp16(A + (size_t)(m0 + r) * H_DIM + kk * 64 + sc,
                   Ab[bufi] + pp * 2048 + w * 512);
        async_cp16(Bm + (size_t)(n0 + r) * H_DIM + kk * 64 + sc,
                   Bb[bufi] + pp * 2048 + w * 512);
      }
    };
    auto kchunk = [&](int bufi) {
      const u16* Ap = Ab[bufi];
      const u16* Bp = Bb[bufi];
#pragma unroll
      for (int ks = 0; ks < 2; ++ks) {
        const int c = ks * 32 + lrow * 8;
        bf16x8 a0 = *(const bf16x8*)(Ap + rA0 * 64 + (c ^ sA0));
        bf16x8 a1 = *(const bf16x8*)(Ap + rA1 * 64 + (c ^ sA1));
        bf16x8 b0 = *(const bf16x8*)(Bp + rB0 * 64 + (c ^ sB0));
        bf16x8 b1 = *(const bf16x8*)(Bp + rB1 * 64 + (c ^ sB1));
        acc[0][0] = __builtin_amdgcn_mfma_f32_16x16x32_bf16(a0, b0, acc[0][0], 0, 0, 0);
        acc[0][1] = __builtin_amdgcn_mfma_f32_16x16x32_bf16(a0, b1, acc[0][1], 0, 0, 0);
        acc[1][0] = __builtin_amdgcn_mfma_f32_16x16x32_bf16(a1, b0, acc[1][0], 0, 0, 0);
        acc[1][1] = __builtin_amdgcn_mfma_f32_16x16x32_bf16(a1, b1, acc[1][1], 0, 0, 0);
      }
    };
    stage(0, 0);
    stage(1, 1);
    stage(2, 2);
#pragma unroll
    for (int kk = 0; kk < 16; ++kk) {
      // outstanding: 3 chunks x 4 loads = 12 (kk<=13), 8 (kk=14), 4 (kk=15)
      if (kk <= 13)      asm volatile("s_waitcnt vmcnt(8)" ::: "memory");
      else if (kk == 14) asm volatile("s_waitcnt vmcnt(4)" ::: "memory");
      else               asm volatile("s_waitcnt vmcnt(0)" ::: "memory");
      __builtin_amdgcn_s_barrier();   // chunk kk LDS-visible to all waves
      kchunk(kk % 3);
      __builtin_amdgcn_s_barrier();   // all reads of buf kk%3 done
      if (kk <= 12) stage(kk + 3, kk % 3);
    }
  }

  float bv0 = bias[n0 + nq + lcol], bv1 = bias[n0 + nq + 16 + lcol];
  if (!out_f32) {
    // assemble bf16 tile in LDS, then coalesced 32B/thread stores
    u16* At = Ab[0];
#pragma unroll
    for (int mt = 0; mt < 2; ++mt)
#pragma unroll
      for (int rr = 0; rr < 4; ++rr) {
        int rowl = mq + mt * 16 + lrow * 4 + rr;  // tile-local row
#pragma unroll
        for (int nt = 0; nt < 2; ++nt) {
          int coll = nq + nt * 16 + lcol;
          float v = acc[mt][nt][rr] + (nt ? bv1 : bv0);
          if (xrow != nullptr)
            v += bf2f(xrow[(size_t)(m0 + rowl) * H_DIM + n0 + coll]);
          if (do_tanh) v = fast_tanh(v);
          At[rowl * 64 + coll] = f2bf(v);
        }
      }
    __syncthreads();
    int row = tid >> 2, ce = (tid & 3) * 16;
    const uint4* src = (const uint4*)(At + row * 64 + ce);
    uint4* gp = (uint4*)((u16*)outp + (size_t)(m0 + row) * H_DIM + n0 + ce);
    gp[0] = src[0];
    gp[1] = src[1];
  } else {
#pragma unroll
    for (int mt = 0; mt < 2; ++mt)
#pragma unroll
      for (int rr = 0; rr < 4; ++rr) {
        int row = m0 + mq + mt * 16 + lrow * 4 + rr;
#pragma unroll
        for (int nt = 0; nt < 2; ++nt) {
          int col = n0 + nq + nt * 16 + lcol;
          float v = acc[mt][nt][rr] + (nt ? bv1 : bv0);
          if (xrow != nullptr) v += bf2f(xrow[(size_t)row * H_DIM + col]);
          if (do_tanh) v = fast_tanh(v);
          ((float*)outp)[(size_t)row * O_DIM + col] = v;
        }
      }
  }
}

// ---------------------------------------------------------------------------
extern "C" void kernel_launch(void* const* d_in, const int* in_sizes, int n_in,
                              void* d_out, int out_size, void* d_ws, size_t ws_size,
                              hipStream_t stream) {
  const float* msg  = (const float*)d_in[0];
  const float* Wemb = (const float*)d_in[1];
  const float* bemb = (const float*)d_in[2];
  const float* Wih  = (const float*)d_in[3];
  const float* bih  = (const float*)d_in[4];
  const float* Whh  = (const float*)d_in[5];
  const float* bhh  = (const float*)d_in[6];
  const float* Wout = (const float*)d_in[7];
  const float* bout = (const float*)d_in[8];
  char* ws = (char*)d_ws;

  // ws layout (bytes)
  float* bc   = (float*)ws;               // 4 KB
  u16* Wc     = (u16*)(ws + 4096);        // 2 MB
  u16* Whh_b  = (u16*)(ws + 2101248);     // 2 MB
  u16* Wout_b = (u16*)(ws + 4198400);     // 2 MB
  u16* hA     = (u16*)(ws + 6295552);     // 2 MB
  u16* hB     = (u16*)(ws + 8392704);     // 2 MB
  u16* xp     = (u16*)(ws + 10489856);    // 64 MB
  const size_t NEED = 10489856 + 67108864;
  if (ws_size < NEED) return;

  convert_w2<<<512, 256, 0, stream>>>(Whh, Wout, Whh_b, Wout_b);
  wcomb_valu<<<dim3(16, 16), 256, 0, stream>>>(Wih, Wemb, Wc);
  bcomb_valu<<<4, 256, 0, stream>>>(Wih, bemb, bih, bc);
  xproj_mfma<<<dim3(8, 256), 256, 0, stream>>>(msg, Wc, bc, xp);

  // t=0: h1 = tanh(x0 + b_hh)  (A=null -> acc=0)
  step_mfma<<<dim3(16, 16), 256, 0, stream>>>(nullptr, Whh_b, xp, bhh, hA, 0, 1);
  for (int t = 1; t < 32; ++t) {
    const u16* hin = (t & 1) ? hA : hB;
    u16* hout = (t & 1) ? hB : hA;
    step_mfma<<<dim3(16, 16), 256, 0, stream>>>(
        hin, Whh_b, xp + (size_t)t * B_DIM * H_DIM, bhh, hout, 0, 1);
  }
  // out = h_T . W_out^T + b_out  (h_T in hB after t=31), fp32 out
  step_mfma<<<dim3(16, 16), 256, 0, stream>>>(hB, Wout_b, nullptr, bout, d_out, 1, 0);
}

// Round 6
// 849.916 us; speedup vs baseline: 3.6323x; 1.0379x over previous
//
#include <hip/hip_runtime.h>
#include <cstdint>
#include <cstddef>

// Problem dims (fixed). Inputs fp32, output fp32.
#define B_DIM 1024
#define T_DIM 32
#define V_DIM 1024
#define E_DIM 512
#define H_DIM 1024
#define O_DIM 1024

typedef unsigned short u16;
typedef __attribute__((ext_vector_type(8))) __bf16 bf16x8;  // MFMA A/B frag
typedef __attribute__((ext_vector_type(4))) float f32x4;    // MFMA C/D frag

__device__ __forceinline__ float bf2f(u16 u) {
  union { unsigned int i; float f; } v; v.i = ((unsigned int)u) << 16; return v.f;
}
__device__ __forceinline__ u16 f2bf(float f) {
  union { float f; unsigned int i; } v; v.f = f;
  return (u16)((v.i + 0x7fffu + ((v.i >> 16) & 1u)) >> 16);  // RNE
}
// async global->LDS, 16B/lane; HW writes lds_base + lane*16 (wave-uniform base)
__device__ __forceinline__ void async_cp16(const void* g, void* l) {
  __builtin_amdgcn_global_load_lds(
      (const __attribute__((address_space(1))) void*)g,
      (__attribute__((address_space(3))) void*)l, 16, 0, 0);
}
// fast tanh via hw exp+rcp: exact at +-inf, |err| ~1e-6 (<< bf16 ulp)
__device__ __forceinline__ float fast_tanh(float v) {
  return 1.f - 2.f / (__expf(2.f * v) + 1.f);
}

// ---------------------------------------------------------------------------
// Convert W_hh, W_out (and msg if dmsg != null) fp32 -> bf16, grid-stride.
// ---------------------------------------------------------------------------
__global__ __launch_bounds__(256) void convert_all(
    const float* __restrict__ Whh, const float* __restrict__ Wout,
    const float* __restrict__ msg, u16* __restrict__ dWhh,
    u16* __restrict__ dWout, u16* __restrict__ dmsg) {
  const int QW = 262144;            // 1M elems / 4
  const int QM = 8388608;           // 32M elems / 4
  const int total = dmsg ? (2 * QW + QM) : (2 * QW);
  int i = blockIdx.x * 256 + threadIdx.x;
  const int stride = gridDim.x * 256;
  for (; i < total; i += stride) {
    const float4* src; ushort4* dst; int j;
    if (i < QW)            { src = (const float4*)Whh;  dst = (ushort4*)dWhh;  j = i; }
    else if (i < 2 * QW)   { src = (const float4*)Wout; dst = (ushort4*)dWout; j = i - QW; }
    else                   { src = (const float4*)msg;  dst = (ushort4*)dmsg;  j = i - 2 * QW; }
    float4 v = src[j];
    ushort4 o = {f2bf(v.x), f2bf(v.y), f2bf(v.z), f2bf(v.w)};
    dst[j] = o;
  }
}

// ---------------------------------------------------------------------------
// W_comb[h][v] = sum_e W_ih[h][e] * W_emb[e][v]  (VALU, verified)
// ---------------------------------------------------------------------------
__global__ __launch_bounds__(256) void wcomb_valu(
    const float* __restrict__ Wih, const float* __restrict__ Wemb,
    u16* __restrict__ Wc) {
  __shared__ __align__(16) float As[16][68];
  __shared__ __align__(16) float Bs[16][68];
  const int tx = threadIdx.x & 15, ty = threadIdx.x >> 4;
  const int v0 = blockIdx.x * 64, h0 = blockIdx.y * 64;
  float acc[4][4] = {};
  for (int kt = 0; kt < 32; ++kt) {  // K = 512
#pragma unroll
    for (int i = 0; i < 4; ++i) {
      int idx = threadIdx.x + i * 256;
      int row = idx >> 4, k = idx & 15;
      As[k][row] = Wih[(size_t)(h0 + row) * E_DIM + kt * 16 + k];
      Bs[k][row] = Wemb[(size_t)(kt * 16 + k) * V_DIM + v0 + row];
    }
    __syncthreads();
    for (int k = 0; k < 16; ++k) {
      float4 a = *(const float4*)&As[k][ty * 4];
      float4 b = *(const float4*)&Bs[k][tx * 4];
      const float av[4] = {a.x, a.y, a.z, a.w}, bv[4] = {b.x, b.y, b.z, b.w};
#pragma unroll
      for (int i = 0; i < 4; ++i)
#pragma unroll
        for (int j = 0; j < 4; ++j) acc[i][j] += av[i] * bv[j];
    }
    __syncthreads();
  }
#pragma unroll
  for (int i = 0; i < 4; ++i)
#pragma unroll
    for (int j = 0; j < 4; ++j)
      Wc[(size_t)(h0 + ty * 4 + i) * V_DIM + v0 + tx * 4 + j] = f2bf(acc[i][j]);
}

// b_comb[h] = W_ih[h,:].b_emb + b_ih[h]  (all fp32)
__global__ __launch_bounds__(256) void bcomb_valu(
    const float* __restrict__ Wih, const float* __restrict__ bemb,
    const float* __restrict__ bih, float* __restrict__ bc) {
  int h = blockIdx.x * 256 + threadIdx.x;  // grid 4
  float s = 0.f;
  for (int e = 0; e < E_DIM; ++e) s += Wih[(size_t)h * E_DIM + e] * bemb[e];
  bc[h] = s + bih[h];
}

// ---------------------------------------------------------------------------
// Unified fully-async 128x128 GEMM: out = f(A[M,1024] . Bm[N,1024]^T ...).
// A, Bm bf16, K-contig. Depth-3 pipeline, counted vmcnt(16), 2 raw barriers
// per 64-wide K-chunk, XOR-swizzled LDS via pre-swizzled global source.
// MODE 0: xproj epilogue (+bias, scatter to xp[t][b][h], bf16)
// MODE 1: RNN step (+bias +x_t tile (LDS-prefetched), tanh, bf16, coalesced)
// MODE 2: output GEMM (+bias, fp32)
// A == nullptr -> acc = 0 (t=0 step).
// LDS: 3 x 32KB chunk bufs (A 16K + B 16K) + 32KB x-tile (MODE1) = 96/128 KB.
// ---------------------------------------------------------------------------
template <int MODE>
__global__ __launch_bounds__(256) void gemm_bt(
    const u16* __restrict__ A, const u16* __restrict__ Bm,
    const u16* __restrict__ x, const float* __restrict__ bias,
    void* __restrict__ outp) {
  constexpr int LDSE = (MODE == 1) ? 65536 : 49152;  // u16 elems
  __shared__ __align__(16) u16 lds[LDSE];
  const int tid = threadIdx.x, lane = tid & 63, w = tid >> 6;
  const int lrow = lane >> 4, lcol = lane & 15;
  const int l7 = lane & 7, r8 = lane >> 3;
  const int p = blockIdx.x;
  int mt, nt;
  if (MODE == 0) {  // XCD remap: xcd k owns a 32-m-tile band (FETCH-verified R5)
    int xk = p & 7, q = p >> 3;
    mt = xk * 32 + (q >> 3);
    nt = q & 7;
  } else {          // 64 blocks: same-XCD blocks share the A m-band
    mt = p & 7;
    nt = p >> 3;
  }
  const int m0 = mt * 128, n0 = nt * 128;
  const int mq = (w & 1) * 64, nq = (w >> 1) * 64;
  const int half = w >> 1, wv = w & 1;  // waves 0,1 stage A; 2,3 stage B

  auto stage = [&](int kk, int d) {
    const u16* src = half ? Bm : A;
    const int rbase = half ? n0 : m0;
#pragma unroll
    for (int i = 0; i < 8; ++i) {
      int row = wv * 64 + i * 8 + r8;  // tile-local, 8-aligned groups
      async_cp16(src + (size_t)(rbase + row) * H_DIM + kk * 64 + ((l7 ^ r8) << 3),
                 lds + d * 16384 + half * 8192 + (wv * 64 + i * 8) * 64);
    }
  };
  auto stage_x = [&]() {  // 128x128 bf16 x-tile, linear
#pragma unroll
    for (int i = 0; i < 8; ++i)
      async_cp16(x + (size_t)(m0 + w * 32 + i * 4 + (lane >> 4)) * H_DIM +
                     n0 + (lane & 15) * 8,
                 lds + 49152 + (w * 32 + i * 4) * 128);
  };

  f32x4 acc[4][4] = {};
  auto kchunk = [&](int d) {
    const u16* base = lds + d * 16384;
#pragma unroll
    for (int ks = 0; ks < 2; ++ks) {
      const int ce = ks * 32 + lrow * 8;
      bf16x8 a[4], b[4];
#pragma unroll
      for (int i = 0; i < 4; ++i) {
        int row = mq + i * 16 + lcol;
        a[i] = *(const bf16x8*)(base + row * 64 + (ce ^ ((row & 7) << 3)));
      }
#pragma unroll
      for (int i = 0; i < 4; ++i) {
        int row = nq + i * 16 + lcol;
        b[i] = *(const bf16x8*)(base + 8192 + row * 64 + (ce ^ ((row & 7) << 3)));
      }
#pragma unroll
      for (int i = 0; i < 4; ++i)
#pragma unroll
        for (int j = 0; j < 4; ++j)
          acc[i][j] = __builtin_amdgcn_mfma_f32_16x16x32_bf16(a[i], b[j], acc[i][j], 0, 0, 0);
    }
  };

  if (A != nullptr) {
    if (MODE == 1 && x != nullptr) stage_x();  // oldest in queue
    stage(0, 0); stage(1, 1); stage(2, 2);
#pragma unroll
    for (int kk = 0; kk < 16; ++kk) {
      // 8 loads/thread/chunk; after wait: chunks kk+1,kk+2 may stay in flight
      if (kk <= 13)      asm volatile("s_waitcnt vmcnt(16)" ::: "memory");
      else if (kk == 14) asm volatile("s_waitcnt vmcnt(8)" ::: "memory");
      else               asm volatile("s_waitcnt vmcnt(0)" ::: "memory");
      __builtin_amdgcn_s_barrier();   // chunk kk LDS-visible to all waves
      kchunk(kk % 3);
      __builtin_amdgcn_s_barrier();   // all reads of buf kk%3 done
      if (kk <= 12) stage(kk + 3, kk % 3);
    }
  } else {
    if (MODE == 1 && x != nullptr) stage_x();
    asm volatile("s_waitcnt vmcnt(0)" ::: "memory");
    __builtin_amdgcn_s_barrier();
  }

  float bv[4];
#pragma unroll
  for (int j = 0; j < 4; ++j) bv[j] = bias[n0 + nq + j * 16 + lcol];

  if (MODE == 0) {  // scatter to xp[t][b][h]
#pragma unroll
    for (int i = 0; i < 4; ++i)
#pragma unroll
      for (int rr = 0; rr < 4; ++rr) {
        int rg = m0 + mq + i * 16 + lrow * 4 + rr;  // flat (b*T + t)
        int bI = rg >> 5, tI = rg & 31;
        u16* dst = (u16*)outp + ((size_t)tI * B_DIM + bI) * H_DIM + n0 + nq;
#pragma unroll
        for (int j = 0; j < 4; ++j)
          dst[j * 16 + lcol] = f2bf(acc[i][j][rr] + bv[j]);
      }
  } else if (MODE == 2) {  // fp32 out
#pragma unroll
    for (int i = 0; i < 4; ++i)
#pragma unroll
      for (int rr = 0; rr < 4; ++rr) {
        int row = m0 + mq + i * 16 + lrow * 4 + rr;
#pragma unroll
        for (int j = 0; j < 4; ++j)
          ((float*)outp)[(size_t)row * O_DIM + n0 + nq + j * 16 + lcol] =
              acc[i][j][rr] + bv[j];
      }
  } else {  // MODE 1: h = tanh(acc + bias + x); assemble in LDS, coalesced out
#pragma unroll
    for (int i = 0; i < 4; ++i)
#pragma unroll
      for (int rr = 0; rr < 4; ++rr) {
        int rowl = mq + i * 16 + lrow * 4 + rr;
#pragma unroll
        for (int j = 0; j < 4; ++j) {
          int col = nq + j * 16 + lcol;
          float v = acc[i][j][rr] + bv[j] + bf2f(lds[49152 + rowl * 128 + col]);
          lds[rowl * 128 + col] = f2bf(fast_tanh(v));  // obuf = buf0 (reads done)
        }
      }
    __syncthreads();
    {
      int row = tid >> 1, c0 = (tid & 1) * 64;  // 128 B/thread, coalesced
      const uint4* s = (const uint4*)(lds + row * 128 + c0);
      uint4* g = (uint4*)((u16*)outp + (size_t)(m0 + row) * H_DIM + n0 + c0);
#pragma unroll
      for (int j = 0; j < 8; ++j) g[j] = s[j];
    }
  }
}

// ---------------------------------------------------------------------------
// FALLBACK xproj (verified R5) for small workspace: fp32 A reg-staged.
// ---------------------------------------------------------------------------
__global__ __launch_bounds__(256) void xproj_mfma(
    const float* __restrict__ msg, const u16* __restrict__ Wc,
    const float* __restrict__ bc, u16* __restrict__ xp) {
  __shared__ u16 As[128 * 64];
  __shared__ u16 Bs[128 * 64];
  const int tid = threadIdx.x, lane = tid & 63, w = tid >> 6;
  const int lrow = lane >> 4, lcol = lane & 15;
  const int p = blockIdx.y * gridDim.x + blockIdx.x;
  const int xk = p & 7, q = p >> 3;
  const int m0 = (xk * 32 + (q >> 3)) * 128;
  const int n0 = (q & 7) * 128;
  const int mq = (w & 1) * 64, nq = (w >> 1) * 64;
  f32x4 acc[4][4] = {};
  const int r8 = lane >> 3, l7 = lane & 7;
  const int ar = tid >> 1, ak = (tid & 1) * 32;

  auto stageB = [&](int kk) {
#pragma unroll
    for (int i = 0; i < 4; ++i) {
      int ch = w * 4 + i;
      async_cp16(Wc + (size_t)(n0 + ch * 8 + r8) * V_DIM + kk * 64 + ((l7 ^ r8) << 3),
                 Bs + ch * 512);
    }
  };
  float4 areg[8];
  auto loadA = [&](int kk) {
    const float4* src = (const float4*)(msg + (size_t)(m0 + ar) * V_DIM + kk * 64 + ak);
#pragma unroll
    for (int i = 0; i < 8; ++i) areg[i] = src[i];
  };
  auto writeA = [&]() {
    u16 tmp[32];
#pragma unroll
    for (int i = 0; i < 8; ++i) {
      tmp[i * 4 + 0] = f2bf(areg[i].x);
      tmp[i * 4 + 1] = f2bf(areg[i].y);
      tmp[i * 4 + 2] = f2bf(areg[i].z);
      tmp[i * 4 + 3] = f2bf(areg[i].w);
    }
#pragma unroll
    for (int i = 0; i < 4; ++i) {
      int c = (ak + i * 8) ^ ((ar & 7) << 3);
      *(uint4*)(As + (size_t)ar * 64 + c) = *(const uint4*)(tmp + i * 8);
    }
  };

  loadA(0);
  stageB(0);
  writeA();
  for (int kk = 0; kk < 16; ++kk) {
    __syncthreads();
    if (kk < 15) loadA(kk + 1);
#pragma unroll
    for (int ks = 0; ks < 2; ++ks) {
      const int kb = ks * 32 + lrow * 8;
      bf16x8 a[4], b[4];
#pragma unroll
      for (int i = 0; i < 4; ++i) {
        int row = mq + i * 16 + lcol;
        a[i] = *(const bf16x8*)(As + row * 64 + (kb ^ ((row & 7) << 3)));
      }
#pragma unroll
      for (int i = 0; i < 4; ++i) {
        int row = nq + i * 16 + lcol;
        b[i] = *(const bf16x8*)(Bs + row * 64 + (kb ^ ((row & 7) << 3)));
      }
#pragma unroll
      for (int i = 0; i < 4; ++i)
#pragma unroll
        for (int j = 0; j < 4; ++j)
          acc[i][j] = __builtin_amdgcn_mfma_f32_16x16x32_bf16(a[i], b[j], acc[i][j], 0, 0, 0);
    }
    __syncthreads();
    if (kk < 15) { stageB(kk + 1); writeA(); }
  }
  float bcv[4];
#pragma unroll
  for (int j = 0; j < 4; ++j) bcv[j] = bc[n0 + nq + j * 16 + lcol];
#pragma unroll
  for (int i = 0; i < 4; ++i)
#pragma unroll
    for (int rr = 0; rr < 4; ++rr) {
      int rg = m0 + mq + i * 16 + lrow * 4 + rr;
      int bI = rg >> 5, tI = rg & 31;
      u16* dst = xp + ((size_t)tI * B_DIM + bI) * H_DIM + n0 + nq;
#pragma unroll
      for (int j = 0; j < 4; ++j)
        dst[j * 16 + lcol] = f2bf(acc[i][j][rr] + bcv[j]);
    }
}

// ---------------------------------------------------------------------------
extern "C" void kernel_launch(void* const* d_in, const int* in_sizes, int n_in,
                              void* d_out, int out_size, void* d_ws, size_t ws_size,
                              hipStream_t stream) {
  const float* msg  = (const float*)d_in[0];
  const float* Wemb = (const float*)d_in[1];
  const float* bemb = (const float*)d_in[2];
  const float* Wih  = (const float*)d_in[3];
  const float* bih  = (const float*)d_in[4];
  const float* Whh  = (const float*)d_in[5];
  const float* bhh  = (const float*)d_in[6];
  const float* Wout = (const float*)d_in[7];
  const float* bout = (const float*)d_in[8];
  char* ws = (char*)d_ws;

  // ws layout (bytes)
  float* bc   = (float*)ws;               // 4 KB
  u16* Wc     = (u16*)(ws + 4096);        // 2 MB
  u16* Whh_b  = (u16*)(ws + 2101248);     // 2 MB
  u16* Wout_b = (u16*)(ws + 4198400);     // 2 MB
  u16* hA     = (u16*)(ws + 6295552);     // 2 MB
  u16* hB     = (u16*)(ws + 8392704);     // 2 MB
  u16* xp     = (u16*)(ws + 10489856);    // 64 MB
  u16* msgb   = (u16*)(ws + 77598720);    // 64 MB (only if ws is big enough)
  const size_t NEED_SMALL = 77598720;
  const size_t NEED_BIG   = 77598720 + 67108864;
  if (ws_size < NEED_SMALL) return;
  const bool big = ws_size >= NEED_BIG;

  if (big) {
    convert_all<<<2048, 256, 0, stream>>>(Whh, Wout, msg, Whh_b, Wout_b, msgb);
  } else {
    convert_all<<<512, 256, 0, stream>>>(Whh, Wout, nullptr, Whh_b, Wout_b, nullptr);
  }
  wcomb_valu<<<dim3(16, 16), 256, 0, stream>>>(Wih, Wemb, Wc);
  bcomb_valu<<<4, 256, 0, stream>>>(Wih, bemb, bih, bc);

  if (big) {
    gemm_bt<0><<<2048, 256, 0, stream>>>(msgb, Wc, nullptr, bc, xp);
  } else {
    xproj_mfma<<<dim3(8, 256), 256, 0, stream>>>(msg, Wc, bc, xp);
  }

  // t=0: h1 = tanh(x0 + b_hh)  (A=null -> acc=0)
  gemm_bt<1><<<64, 256, 0, stream>>>(nullptr, Whh_b, xp, bhh, hA);
  for (int t = 1; t < 32; ++t) {
    const u16* hin = (t & 1) ? hA : hB;
    u16* hout = (t & 1) ? hB : hA;
    gemm_bt<1><<<64, 256, 0, stream>>>(hin, Whh_b,
                                       xp + (size_t)t * B_DIM * H_DIM, bhh, hout);
  }
  // out = h_T . W_out^T + b_out  (h_T in hB after t=31), fp32 out
  gemm_bt<2><<<64, 256, 0, stream>>>(hB, Wout_b, nullptr, bout, d_out);
}

// Round 7
// 566.918 us; speedup vs baseline: 5.4454x; 1.4992x over previous
//
#include <hip/hip_runtime.h>
#include <cstdint>
#include <cstddef>

// Problem dims (fixed). Inputs fp32, output fp32.
#define B_DIM 1024
#define T_DIM 32
#define V_DIM 1024
#define E_DIM 512
#define H_DIM 1024
#define O_DIM 1024

typedef unsigned short u16;
typedef __attribute__((ext_vector_type(8))) __bf16 bf16x8;  // MFMA A/B frag
typedef __attribute__((ext_vector_type(4))) float f32x4;    // MFMA C/D frag

__device__ __forceinline__ float bf2f(u16 u) {
  union { unsigned int i; float f; } v; v.i = ((unsigned int)u) << 16; return v.f;
}
__device__ __forceinline__ u16 f2bf(float f) {
  union { float f; unsigned int i; } v; v.f = f;
  return (u16)((v.i + 0x7fffu + ((v.i >> 16) & 1u)) >> 16);  // RNE
}
// async global->LDS, 16B/lane; HW writes lds_base + lane*16 (wave-uniform base)
__device__ __forceinline__ void async_cp16(const void* g, void* l) {
  __builtin_amdgcn_global_load_lds(
      (const __attribute__((address_space(1))) void*)g,
      (__attribute__((address_space(3))) void*)l, 16, 0, 0);
}
// fast tanh via hw exp+rcp: exact at +-inf, |err| ~1e-6 (<< bf16 ulp)
__device__ __forceinline__ float fast_tanh(float v) {
  return 1.f - 2.f / (__expf(2.f * v) + 1.f);
}

// ---------------------------------------------------------------------------
// Convert W_hh, W_out (and msg if dmsg != null) fp32 -> bf16, grid-stride.
// ---------------------------------------------------------------------------
__global__ __launch_bounds__(256) void convert_all(
    const float* __restrict__ Whh, const float* __restrict__ Wout,
    const float* __restrict__ msg, u16* __restrict__ dWhh,
    u16* __restrict__ dWout, u16* __restrict__ dmsg) {
  const int QW = 262144;            // 1M elems / 4
  const int QM = 8388608;           // 32M elems / 4
  const int total = dmsg ? (2 * QW + QM) : (2 * QW);
  int i = blockIdx.x * 256 + threadIdx.x;
  const int stride = gridDim.x * 256;
  for (; i < total; i += stride) {
    const float4* src; ushort4* dst; int j;
    if (i < QW)            { src = (const float4*)Whh;  dst = (ushort4*)dWhh;  j = i; }
    else if (i < 2 * QW)   { src = (const float4*)Wout; dst = (ushort4*)dWout; j = i - QW; }
    else                   { src = (const float4*)msg;  dst = (ushort4*)dmsg;  j = i - 2 * QW; }
    float4 v = src[j];
    ushort4 o = {f2bf(v.x), f2bf(v.y), f2bf(v.z), f2bf(v.w)};
    dst[j] = o;
  }
}

// ---------------------------------------------------------------------------
// W_comb[h][v] = sum_e W_ih[h][e] * W_emb[e][v]  (VALU, verified)
// ---------------------------------------------------------------------------
__global__ __launch_bounds__(256) void wcomb_valu(
    const float* __restrict__ Wih, const float* __restrict__ Wemb,
    u16* __restrict__ Wc) {
  __shared__ __align__(16) float As[16][68];
  __shared__ __align__(16) float Bs[16][68];
  const int tx = threadIdx.x & 15, ty = threadIdx.x >> 4;
  const int v0 = blockIdx.x * 64, h0 = blockIdx.y * 64;
  float acc[4][4] = {};
  for (int kt = 0; kt < 32; ++kt) {  // K = 512
#pragma unroll
    for (int i = 0; i < 4; ++i) {
      int idx = threadIdx.x + i * 256;
      int row = idx >> 4, k = idx & 15;
      As[k][row] = Wih[(size_t)(h0 + row) * E_DIM + kt * 16 + k];
      Bs[k][row] = Wemb[(size_t)(kt * 16 + k) * V_DIM + v0 + row];
    }
    __syncthreads();
    for (int k = 0; k < 16; ++k) {
      float4 a = *(const float4*)&As[k][ty * 4];
      float4 b = *(const float4*)&Bs[k][tx * 4];
      const float av[4] = {a.x, a.y, a.z, a.w}, bv[4] = {b.x, b.y, b.z, b.w};
#pragma unroll
      for (int i = 0; i < 4; ++i)
#pragma unroll
        for (int j = 0; j < 4; ++j) acc[i][j] += av[i] * bv[j];
    }
    __syncthreads();
  }
#pragma unroll
  for (int i = 0; i < 4; ++i)
#pragma unroll
    for (int j = 0; j < 4; ++j)
      Wc[(size_t)(h0 + ty * 4 + i) * V_DIM + v0 + tx * 4 + j] = f2bf(acc[i][j]);
}

// b_comb[h] = W_ih[h,:].b_emb + b_ih[h]  (all fp32)
__global__ __launch_bounds__(256) void bcomb_valu(
    const float* __restrict__ Wih, const float* __restrict__ bemb,
    const float* __restrict__ bih, float* __restrict__ bc) {
  int h = blockIdx.x * 256 + threadIdx.x;  // grid 4
  float s = 0.f;
  for (int e = 0; e < E_DIM; ++e) s += Wih[(size_t)h * E_DIM + e] * bemb[e];
  bc[h] = s + bih[h];
}

// ---------------------------------------------------------------------------
// xproj GEMM (verified R6, 98 us): 128x128 tiles, depth-3 counted vmcnt,
// XOR-swizzled LDS, XCD band remap. out = msgb . Wc^T + bc -> xp scatter.
// ---------------------------------------------------------------------------
template <int MODE>
__global__ __launch_bounds__(256) void gemm_bt(
    const u16* __restrict__ A, const u16* __restrict__ Bm,
    const u16* __restrict__ x, const float* __restrict__ bias,
    void* __restrict__ outp) {
  constexpr int LDSE = 49152;  // u16 elems
  __shared__ __align__(16) u16 lds[LDSE];
  const int tid = threadIdx.x, lane = tid & 63, w = tid >> 6;
  const int lrow = lane >> 4, lcol = lane & 15;
  const int l7 = lane & 7, r8 = lane >> 3;
  const int p = blockIdx.x;
  int mt, nt;
  {  // XCD remap: xcd k owns a 32-m-tile band (FETCH-verified R5/R6)
    int xk = p & 7, q = p >> 3;
    mt = xk * 32 + (q >> 3);
    nt = q & 7;
  }
  const int m0 = mt * 128, n0 = nt * 128;
  const int mq = (w & 1) * 64, nq = (w >> 1) * 64;
  const int half = w >> 1, wv = w & 1;  // waves 0,1 stage A; 2,3 stage B

  auto stage = [&](int kk, int d) {
    const u16* src = half ? Bm : A;
    const int rbase = half ? n0 : m0;
#pragma unroll
    for (int i = 0; i < 8; ++i) {
      int row = wv * 64 + i * 8 + r8;  // tile-local, 8-aligned groups
      async_cp16(src + (size_t)(rbase + row) * H_DIM + kk * 64 + ((l7 ^ r8) << 3),
                 lds + d * 16384 + half * 8192 + (wv * 64 + i * 8) * 64);
    }
  };

  f32x4 acc[4][4] = {};
  auto kchunk = [&](int d) {
    const u16* base = lds + d * 16384;
#pragma unroll
    for (int ks = 0; ks < 2; ++ks) {
      const int ce = ks * 32 + lrow * 8;
      bf16x8 a[4], b[4];
#pragma unroll
      for (int i = 0; i < 4; ++i) {
        int row = mq + i * 16 + lcol;
        a[i] = *(const bf16x8*)(base + row * 64 + (ce ^ ((row & 7) << 3)));
      }
#pragma unroll
      for (int i = 0; i < 4; ++i) {
        int row = nq + i * 16 + lcol;
        b[i] = *(const bf16x8*)(base + 8192 + row * 64 + (ce ^ ((row & 7) << 3)));
      }
#pragma unroll
      for (int i = 0; i < 4; ++i)
#pragma unroll
        for (int j = 0; j < 4; ++j)
          acc[i][j] = __builtin_amdgcn_mfma_f32_16x16x32_bf16(a[i], b[j], acc[i][j], 0, 0, 0);
    }
  };

  stage(0, 0); stage(1, 1); stage(2, 2);
#pragma unroll
  for (int kk = 0; kk < 16; ++kk) {
    if (kk <= 13)      asm volatile("s_waitcnt vmcnt(16)" ::: "memory");
    else if (kk == 14) asm volatile("s_waitcnt vmcnt(8)" ::: "memory");
    else               asm volatile("s_waitcnt vmcnt(0)" ::: "memory");
    __builtin_amdgcn_s_barrier();   // chunk kk LDS-visible to all waves
    kchunk(kk % 3);
    __builtin_amdgcn_s_barrier();   // all reads of buf kk%3 done
    if (kk <= 12) stage(kk + 3, kk % 3);
  }

  float bv[4];
#pragma unroll
  for (int j = 0; j < 4; ++j) bv[j] = bias[n0 + nq + j * 16 + lcol];
  // scatter to xp[t][b][h]
#pragma unroll
  for (int i = 0; i < 4; ++i)
#pragma unroll
    for (int rr = 0; rr < 4; ++rr) {
      int rg = m0 + mq + i * 16 + lrow * 4 + rr;  // flat (b*T + t)
      int bI = rg >> 5, tI = rg & 31;
      u16* dst = (u16*)outp + ((size_t)tI * B_DIM + bI) * H_DIM + n0 + nq;
#pragma unroll
      for (int j = 0; j < 4; ++j)
        dst[j * 16 + lcol] = f2bf(acc[i][j][rr] + bv[j]);
    }
}

// ---------------------------------------------------------------------------
// RNN step / output GEMM at 64x64 tiles, grid 256 -> ALL 256 CUs (was 64).
// Same verified machinery: depth-3 counted-vmcnt (4 loads/thread/chunk,
// steady vmcnt(8)), XOR-swizzled staging+reads, x-tile LDS-prefetch (issued
// oldest), LDS-assembled coalesced h-store. XCD swizzle: mt=(p&7)*2+(q>>4)
// so the XCD that WRITES h band m is the XCD that READS it next step, and
// Whh stays L2-resident per XCD across all steps.
// MODE 1: h = tanh(A.Bm^T + bias + x), bf16. MODE 2: out = A.Bm^T+bias, f32.
// A == nullptr -> acc = 0 (t=0). LDS: 3x16KB chunks (+8KB x) = 48/56 KB.
// ---------------------------------------------------------------------------
template <int MODE>
__global__ __launch_bounds__(256) void step64(
    const u16* __restrict__ A, const u16* __restrict__ Bm,
    const u16* __restrict__ x, const float* __restrict__ bias,
    void* __restrict__ outp) {
  constexpr int XOFF = 24576;  // elems
  constexpr int LDSE = (MODE == 1) ? 28672 : 24576;
  __shared__ __align__(16) u16 lds[LDSE];
  const int tid = threadIdx.x, lane = tid & 63, w = tid >> 6;
  const int lrow = lane >> 4, lcol = lane & 15;
  const int l7 = lane & 7, r8 = lane >> 3;
  const int p = blockIdx.x;
  const int xcd = p & 7, q = p >> 3;          // q in 0..31
  const int mt = xcd * 2 + (q >> 4), nt = q & 15;
  const int m0 = mt * 64, n0 = nt * 64;
  const int mq = (w & 1) * 32, nq = (w >> 1) * 32;
  const int half = w >> 1, wv = w & 1;  // waves 0,1 stage A; 2,3 stage B

  auto stage = [&](int kk, int d) {
    const u16* src = half ? Bm : A;
    const int rbase = half ? n0 : m0;
#pragma unroll
    for (int i = 0; i < 4; ++i) {
      int row = wv * 32 + i * 8 + r8;  // tile-local
      async_cp16(src + (size_t)(rbase + row) * H_DIM + kk * 64 + ((l7 ^ r8) << 3),
                 lds + d * 8192 + half * 4096 + (wv * 32 + i * 8) * 64);
    }
  };
  auto stage_x = [&]() {  // 64x64 bf16 x-tile, linear
#pragma unroll
    for (int i = 0; i < 2; ++i)
      async_cp16(x + (size_t)(m0 + i * 32 + w * 8 + r8) * H_DIM + n0 + l7 * 8,
                 lds + XOFF + (i * 32 + w * 8) * 64);
  };

  f32x4 acc[2][2] = {};
  auto kchunk = [&](int d) {
    const u16* base = lds + d * 8192;
#pragma unroll
    for (int ks = 0; ks < 2; ++ks) {
      const int ce = ks * 32 + lrow * 8;
      bf16x8 a[2], b[2];
#pragma unroll
      for (int i = 0; i < 2; ++i) {
        int row = mq + i * 16 + lcol;
        a[i] = *(const bf16x8*)(base + row * 64 + (ce ^ ((row & 7) << 3)));
      }
#pragma unroll
      for (int j = 0; j < 2; ++j) {
        int row = nq + j * 16 + lcol;
        b[j] = *(const bf16x8*)(base + 4096 + row * 64 + (ce ^ ((row & 7) << 3)));
      }
#pragma unroll
      for (int i = 0; i < 2; ++i)
#pragma unroll
        for (int j = 0; j < 2; ++j)
          acc[i][j] = __builtin_amdgcn_mfma_f32_16x16x32_bf16(a[i], b[j], acc[i][j], 0, 0, 0);
    }
  };

  if (A != nullptr) {
    if (MODE == 1) stage_x();  // oldest in queue, drained by kk=0's wait
    stage(0, 0); stage(1, 1); stage(2, 2);
#pragma unroll
    for (int kk = 0; kk < 16; ++kk) {
      // 4 loads/thread/chunk; chunks kk+1, kk+2 stay in flight across barrier
      if (kk <= 13)      asm volatile("s_waitcnt vmcnt(8)" ::: "memory");
      else if (kk == 14) asm volatile("s_waitcnt vmcnt(4)" ::: "memory");
      else               asm volatile("s_waitcnt vmcnt(0)" ::: "memory");
      __builtin_amdgcn_s_barrier();   // chunk kk LDS-visible to all waves
      kchunk(kk % 3);
      __builtin_amdgcn_s_barrier();   // all reads of buf kk%3 done
      if (kk <= 12) stage(kk + 3, kk % 3);
    }
  } else {
    if (MODE == 1) stage_x();
    asm volatile("s_waitcnt vmcnt(0)" ::: "memory");
    __builtin_amdgcn_s_barrier();
  }

  float bv[2] = {bias[n0 + nq + lcol], bias[n0 + nq + 16 + lcol]};
  if (MODE == 2) {  // fp32 out, direct stores (once)
#pragma unroll
    for (int i = 0; i < 2; ++i)
#pragma unroll
      for (int rr = 0; rr < 4; ++rr) {
        int row = m0 + mq + i * 16 + lrow * 4 + rr;
#pragma unroll
        for (int j = 0; j < 2; ++j)
          ((float*)outp)[(size_t)row * O_DIM + n0 + nq + j * 16 + lcol] =
              acc[i][j][rr] + bv[j];
      }
  } else {  // MODE 1: h = tanh(acc + bias + x); assemble in LDS, coalesced out
#pragma unroll
    for (int i = 0; i < 2; ++i)
#pragma unroll
      for (int rr = 0; rr < 4; ++rr) {
        int rowl = mq + i * 16 + lrow * 4 + rr;  // tile-local
#pragma unroll
        for (int j = 0; j < 2; ++j) {
          int col = nq + j * 16 + lcol;
          float v = acc[i][j][rr] + bv[j] + bf2f(lds[XOFF + rowl * 64 + col]);
          lds[rowl * 64 + col] = f2bf(fast_tanh(v));  // buf0: reads done
        }
      }
    __syncthreads();
    {
      int row = tid >> 2, c = (tid & 3) * 16;  // 32 B/thread, coalesced
      const uint4* s = (const uint4*)(lds + row * 64 + c);
      uint4 v0 = s[0], v1 = s[1];
      uint4* g = (uint4*)((u16*)outp + (size_t)(m0 + row) * H_DIM + n0 + c);
      g[0] = v0;
      g[1] = v1;
    }
  }
}

// ---------------------------------------------------------------------------
// FALLBACK xproj (verified R5) for small workspace: fp32 A reg-staged.
// ---------------------------------------------------------------------------
__global__ __launch_bounds__(256) void xproj_mfma(
    const float* __restrict__ msg, const u16* __restrict__ Wc,
    const float* __restrict__ bc, u16* __restrict__ xp) {
  __shared__ u16 As[128 * 64];
  __shared__ u16 Bs[128 * 64];
  const int tid = threadIdx.x, lane = tid & 63, w = tid >> 6;
  const int lrow = lane >> 4, lcol = lane & 15;
  const int p = blockIdx.y * gridDim.x + blockIdx.x;
  const int xk = p & 7, q = p >> 3;
  const int m0 = (xk * 32 + (q >> 3)) * 128;
  const int n0 = (q & 7) * 128;
  const int mq = (w & 1) * 64, nq = (w >> 1) * 64;
  f32x4 acc[4][4] = {};
  const int r8 = lane >> 3, l7 = lane & 7;
  const int ar = tid >> 1, ak = (tid & 1) * 32;

  auto stageB = [&](int kk) {
#pragma unroll
    for (int i = 0; i < 4; ++i) {
      int ch = w * 4 + i;
      async_cp16(Wc + (size_t)(n0 + ch * 8 + r8) * V_DIM + kk * 64 + ((l7 ^ r8) << 3),
                 Bs + ch * 512);
    }
  };
  float4 areg[8];
  auto loadA = [&](int kk) {
    const float4* src = (const float4*)(msg + (size_t)(m0 + ar) * V_DIM + kk * 64 + ak);
#pragma unroll
    for (int i = 0; i < 8; ++i) areg[i] = src[i];
  };
  auto writeA = [&]() {
    u16 tmp[32];
#pragma unroll
    for (int i = 0; i < 8; ++i) {
      tmp[i * 4 + 0] = f2bf(areg[i].x);
      tmp[i * 4 + 1] = f2bf(areg[i].y);
      tmp[i * 4 + 2] = f2bf(areg[i].z);
      tmp[i * 4 + 3] = f2bf(areg[i].w);
    }
#pragma unroll
    for (int i = 0; i < 4; ++i) {
      int c = (ak + i * 8) ^ ((ar & 7) << 3);
      *(uint4*)(As + (size_t)ar * 64 + c) = *(const uint4*)(tmp + i * 8);
    }
  };

  loadA(0);
  stageB(0);
  writeA();
  for (int kk = 0; kk < 16; ++kk) {
    __syncthreads();
    if (kk < 15) loadA(kk + 1);
#pragma unroll
    for (int ks = 0; ks < 2; ++ks) {
      const int kb = ks * 32 + lrow * 8;
      bf16x8 a[4], b[4];
#pragma unroll
      for (int i = 0; i < 4; ++i) {
        int row = mq + i * 16 + lcol;
        a[i] = *(const bf16x8*)(As + row * 64 + (kb ^ ((row & 7) << 3)));
      }
#pragma unroll
      for (int i = 0; i < 4; ++i) {
        int row = nq + i * 16 + lcol;
        b[i] = *(const bf16x8*)(Bs + row * 64 + (kb ^ ((row & 7) << 3)));
      }
#pragma unroll
      for (int i = 0; i < 4; ++i)
#pragma unroll
        for (int j = 0; j < 4; ++j)
          acc[i][j] = __builtin_amdgcn_mfma_f32_16x16x32_bf16(a[i], b[j], acc[i][j], 0, 0, 0);
    }
    __syncthreads();
    if (kk < 15) { stageB(kk + 1); writeA(); }
  }
  float bcv[4];
#pragma unroll
  for (int j = 0; j < 4; ++j) bcv[j] = bc[n0 + nq + j * 16 + lcol];
#pragma unroll
  for (int i = 0; i < 4; ++i)
#pragma unroll
    for (int rr = 0; rr < 4; ++rr) {
      int rg = m0 + mq + i * 16 + lrow * 4 + rr;
      int bI = rg >> 5, tI = rg & 31;
      u16* dst = xp + ((size_t)tI * B_DIM + bI) * H_DIM + n0 + nq;
#pragma unroll
      for (int j = 0; j < 4; ++j)
        dst[j * 16 + lcol] = f2bf(acc[i][j][rr] + bcv[j]);
    }
}

// ---------------------------------------------------------------------------
extern "C" void kernel_launch(void* const* d_in, const int* in_sizes, int n_in,
                              void* d_out, int out_size, void* d_ws, size_t ws_size,
                              hipStream_t stream) {
  const float* msg  = (const float*)d_in[0];
  const float* Wemb = (const float*)d_in[1];
  const float* bemb = (const float*)d_in[2];
  const float* Wih  = (const float*)d_in[3];
  const float* bih  = (const float*)d_in[4];
  const float* Whh  = (const float*)d_in[5];
  const float* bhh  = (const float*)d_in[6];
  const float* Wout = (const float*)d_in[7];
  const float* bout = (const float*)d_in[8];
  char* ws = (char*)d_ws;

  // ws layout (bytes)
  float* bc   = (float*)ws;               // 4 KB
  u16* Wc     = (u16*)(ws + 4096);        // 2 MB
  u16* Whh_b  = (u16*)(ws + 2101248);     // 2 MB
  u16* Wout_b = (u16*)(ws + 4198400);     // 2 MB
  u16* hA     = (u16*)(ws + 6295552);     // 2 MB
  u16* hB     = (u16*)(ws + 8392704);     // 2 MB
  u16* xp     = (u16*)(ws + 10489856);    // 64 MB
  u16* msgb   = (u16*)(ws + 77598720);    // 64 MB (only if ws is big enough)
  const size_t NEED_SMALL = 77598720;
  const size_t NEED_BIG   = 77598720 + 67108864;
  if (ws_size < NEED_SMALL) return;
  const bool big = ws_size >= NEED_BIG;

  if (big) {
    convert_all<<<2048, 256, 0, stream>>>(Whh, Wout, msg, Whh_b, Wout_b, msgb);
  } else {
    convert_all<<<512, 256, 0, stream>>>(Whh, Wout, nullptr, Whh_b, Wout_b, nullptr);
  }
  wcomb_valu<<<dim3(16, 16), 256, 0, stream>>>(Wih, Wemb, Wc);
  bcomb_valu<<<4, 256, 0, stream>>>(Wih, bemb, bih, bc);

  if (big) {
    gemm_bt<0><<<2048, 256, 0, stream>>>(msgb, Wc, nullptr, bc, xp);
  } else {
    xproj_mfma<<<dim3(8, 256), 256, 0, stream>>>(msg, Wc, bc, xp);
  }

  // t=0: h1 = tanh(x0 + b_hh)  (A=null -> acc=0)
  step64<1><<<256, 256, 0, stream>>>(nullptr, Whh_b, xp, bhh, hA);
  for (int t = 1; t < 32; ++t) {
    const u16* hin = (t & 1) ? hA : hB;
    u16* hout = (t & 1) ? hB : hA;
    step64<1><<<256, 256, 0, stream>>>(hin, Whh_b,
                                       xp + (size_t)t * B_DIM * H_DIM, bhh, hout);
  }
  // out = h_T . W_out^T + b_out  (h_T in hB after t=31), fp32 out
  step64<2><<<256, 256, 0, stream>>>(hB, Wout_b, nullptr, bout, d_out);
}